// Round 2
// baseline (267.511 us; speedup 1.0000x reference)
//
#include <hip/hip_runtime.h>
#include <hip/hip_bf16.h>

// ---------------- types ----------------
using bf16x8_t = __attribute__((ext_vector_type(8))) __bf16;
using f32x4_t  = __attribute__((ext_vector_type(4))) float;

#define MFMA16(a, b, c) __builtin_amdgcn_mfma_f32_16x16x32_bf16((a), (b), (c), 0, 0, 0)

// ---------------- problem constants ----------------
constexpr int BATCH   = 2;
constexpr int SEQ     = 2048;
constexpr int DMODEL  = 1024;
constexpr int NHEAD   = 16;
constexpr int DK      = 64;
constexpr int MTOT    = BATCH * SEQ;   // 4096 rows in all GEMMs
constexpr float SM_SCALE = 0.125f;     // 1/sqrt(64)

// fp32 x8 -> bf16 x8 convert (for LDS staging of fp32 global data)
__device__ __forceinline__ bf16x8_t cvt8(const float* __restrict__ p) {
    f32x4_t a = *(const f32x4_t*)p;
    f32x4_t b = *(const f32x4_t*)(p + 4);
    bf16x8_t r;
    r[0] = (__bf16)a[0]; r[1] = (__bf16)a[1]; r[2] = (__bf16)a[2]; r[3] = (__bf16)a[3];
    r[4] = (__bf16)b[0]; r[5] = (__bf16)b[1]; r[6] = (__bf16)b[2]; r[7] = (__bf16)b[3];
    return r;
}

// ================= GEMM: C[M,N] = A[M,K] * Bt[N,K]^T =================================
// A: fp32 or bf16 (template), Bt: fp32 weights, C: bf16 ws or fp32 out (template).
// Tile 128x128, BK=32, 256 threads = 4 waves in 2x2. LDS stride 40 bf16 (16B-aligned
// rows, 2-way bank aliasing only = free per m136).
template<bool A_BF16, bool C_F32>
__device__ __forceinline__ void gemm_body(
    const void* __restrict__ Ap, const float* __restrict__ Bt,
    void* __restrict__ Cp, int m0, int n0)
{
    constexpr int K = DMODEL, N = DMODEL;
    constexpr int LDT = 40;
    __shared__ __bf16 a_sh[128 * LDT];
    __shared__ __bf16 b_sh[128 * LDT];

    const int tid  = threadIdx.x;
    const int wave = tid >> 6, lane = tid & 63;
    const int wm = wave >> 1, wn = wave & 1;
    const int l15 = lane & 15, lhi = lane >> 4;

    f32x4_t acc[4][4] = {};

    for (int k0 = 0; k0 < K; k0 += 32) {
        __syncthreads();
        // stage A and B tiles: 128 rows x 4 groups of 8 elems = 512 slots
        #pragma unroll
        for (int s = 0; s < 2; ++s) {
            int slot = tid + s * 256;
            int row = slot >> 2, grp = slot & 3;
            bf16x8_t va;
            if constexpr (A_BF16)
                va = *(const bf16x8_t*)((const __bf16*)Ap + (size_t)(m0 + row) * K + k0 + grp * 8);
            else
                va = cvt8((const float*)Ap + (size_t)(m0 + row) * K + k0 + grp * 8);
            *(bf16x8_t*)(a_sh + row * LDT + grp * 8) = va;
            bf16x8_t vb = cvt8(Bt + (size_t)(n0 + row) * K + k0 + grp * 8);
            *(bf16x8_t*)(b_sh + row * LDT + grp * 8) = vb;
        }
        __syncthreads();

        bf16x8_t af[4], bfr[4];
        #pragma unroll
        for (int i = 0; i < 4; ++i)
            af[i] = *(const bf16x8_t*)(a_sh + (wm * 64 + i * 16 + l15) * LDT + lhi * 8);
        #pragma unroll
        for (int j = 0; j < 4; ++j)
            bfr[j] = *(const bf16x8_t*)(b_sh + (wn * 64 + j * 16 + l15) * LDT + lhi * 8);
        #pragma unroll
        for (int i = 0; i < 4; ++i)
            #pragma unroll
            for (int j = 0; j < 4; ++j)
                acc[i][j] = MFMA16(af[i], bfr[j], acc[i][j]);
    }

    // C/D layout (m89-verified): col = lane&15, row = (lane>>4)*4 + reg
    #pragma unroll
    for (int i = 0; i < 4; ++i)
        #pragma unroll
        for (int j = 0; j < 4; ++j)
            #pragma unroll
            for (int r = 0; r < 4; ++r) {
                int row = m0 + wm * 64 + i * 16 + lhi * 4 + r;
                int col = n0 + wn * 64 + j * 16 + l15;
                if constexpr (C_F32)
                    ((float*)Cp)[(size_t)row * N + col] = acc[i][j][r];
                else
                    ((__bf16*)Cp)[(size_t)row * N + col] = (__bf16)acc[i][j][r];
            }
}

// QKV projection: fp32 in -> bf16 ws. grid (N/128, M/128, 3)
__global__ __launch_bounds__(256) void proj_qkv_kernel(
    const float* __restrict__ xq, const float* __restrict__ xk, const float* __restrict__ xv,
    const float* __restrict__ wq, const float* __restrict__ wk, const float* __restrict__ wv,
    __bf16* __restrict__ oq, __bf16* __restrict__ ok, __bf16* __restrict__ ov)
{
    const float* A;
    const float* Bt;
    __bf16* C;
    if (blockIdx.z == 0)      { A = xq; Bt = wq; C = oq; }
    else if (blockIdx.z == 1) { A = xk; Bt = wk; C = ok; }
    else                      { A = xv; Bt = wv; C = ov; }
    gemm_body<false, false>(A, Bt, C, blockIdx.y * 128, blockIdx.x * 128);
}

// Output projection: bf16 ctx ws -> fp32 out. grid (N/128, M/128)
__global__ __launch_bounds__(256) void proj_out_kernel(
    const __bf16* __restrict__ ctx, const float* __restrict__ wo, float* __restrict__ out)
{
    gemm_body<true, true>(ctx, wo, out, blockIdx.y * 128, blockIdx.x * 128);
}

// ================= Flash attention (causal) ==========================================
// grid: (SEQ/64, BATCH*NHEAD), 256 threads = 4 waves; each wave owns 16 query rows.
// Q/K/V/O are bf16 [B*S, DMODEL] row-major; head h occupies cols h*64 .. h*64+63.
__global__ __launch_bounds__(256) void attn_kernel(
    const __bf16* __restrict__ Qm, const __bf16* __restrict__ Km,
    const __bf16* __restrict__ Vm, __bf16* __restrict__ Om)
{
    constexpr int LDT = 72;  // 144B row stride: 16B-aligned, 2-way bank aliasing only
    __shared__ __bf16 k_sh[64 * LDT];    // K tile, row-major [kv][d]
    __shared__ __bf16 vt_sh[64 * LDT];   // V tile, transposed [d][kv]
    __shared__ __bf16 p_sh[4][16 * LDT]; // per-wave P tile [16 q rows][64 kv]

    const int tid  = threadIdx.x;
    const int wave = tid >> 6, lane = tid & 63;
    const int l15 = lane & 15, lhi = lane >> 4;

    const int q0 = blockIdx.x * 64;
    const int bh = blockIdx.y;
    const int b = bh >> 4, h = bh & 15;

    const __bf16* Qb = Qm + (size_t)b * SEQ * DMODEL + h * DK;
    const __bf16* Kb = Km + (size_t)b * SEQ * DMODEL + h * DK;
    const __bf16* Vb = Vm + (size_t)b * SEQ * DMODEL + h * DK;

    // Q fragments held in registers: A layout row = lane&15, k = (lane>>4)*8 + j
    bf16x8_t qf[2];
    {
        const __bf16* qp = Qb + (size_t)(q0 + wave * 16 + l15) * DMODEL + lhi * 8;
        qf[0] = *(const bf16x8_t*)(qp);
        qf[1] = *(const bf16x8_t*)(qp + 32);
    }

    f32x4_t acc[4] = {};          // ctx accumulator: row=(lhi*4+r) q, col=n*16+l15 d
    float mrow[4] = {-INFINITY, -INFINITY, -INFINITY, -INFINITY};
    float lrow[4] = {0.f, 0.f, 0.f, 0.f};

    const int ntiles = (q0 >> 6) + 1;
    for (int t = 0; t < ntiles; ++t) {
        const int kv0 = t * 64;
        __syncthreads();   // protect K/V LDS from previous iteration's readers
        // stage K (row-major) and V (transposed): 64 rows x 8 groups = 512 slots
        #pragma unroll
        for (int s = 0; s < 2; ++s) {
            int slot = tid + s * 256;
            int row = slot >> 3, grp = slot & 7;
            bf16x8_t kv8 = *(const bf16x8_t*)(Kb + (size_t)(kv0 + row) * DMODEL + grp * 8);
            *(bf16x8_t*)(k_sh + row * LDT + grp * 8) = kv8;
            bf16x8_t vv8 = *(const bf16x8_t*)(Vb + (size_t)(kv0 + row) * DMODEL + grp * 8);
            #pragma unroll
            for (int j = 0; j < 8; ++j)
                vt_sh[(grp * 8 + j) * LDT + row] = vv8[j];
        }
        __syncthreads();

        // ---- S = Q K^T (per wave: 16 q rows x 64 kv) ----
        f32x4_t sf[4] = {};
        #pragma unroll
        for (int ks = 0; ks < 2; ++ks)
            #pragma unroll
            for (int n = 0; n < 4; ++n) {
                bf16x8_t kf = *(const bf16x8_t*)(k_sh + (n * 16 + l15) * LDT + ks * 32 + lhi * 8);
                sf[n] = MFMA16(qf[ks], kf, sf[n]);
            }

        // ---- scale + causal mask + online softmax ----
        const int qrow_base = q0 + wave * 16 + lhi * 4;
        float pmax[4];
        #pragma unroll
        for (int r = 0; r < 4; ++r) {
            float mx = -3.0e38f;
            #pragma unroll
            for (int n = 0; n < 4; ++n) {
                float sv = sf[n][r] * SM_SCALE;
                int col = kv0 + n * 16 + l15;
                if (col > qrow_base + r) sv = -1.0e30f;
                sf[n][r] = sv;
                mx = fmaxf(mx, sv);
            }
            pmax[r] = mx;
        }
        #pragma unroll
        for (int r = 0; r < 4; ++r)
            #pragma unroll
            for (int off = 1; off < 16; off <<= 1)
                pmax[r] = fmaxf(pmax[r], __shfl_xor(pmax[r], off, 64));

        float rsum[4];
        #pragma unroll
        for (int r = 0; r < 4; ++r) {
            float mnew = fmaxf(mrow[r], pmax[r]);
            float sfac = __expf(mrow[r] - mnew);
            mrow[r] = mnew;
            float rs = 0.f;
            #pragma unroll
            for (int n = 0; n < 4; ++n) {
                float p = __expf(sf[n][r] - mnew);
                sf[n][r] = p;
                rs += p;
            }
            rsum[r] = rs;
            lrow[r] *= sfac;
            #pragma unroll
            for (int n = 0; n < 4; ++n) acc[n][r] *= sfac;
        }
        #pragma unroll
        for (int r = 0; r < 4; ++r) {
            #pragma unroll
            for (int off = 1; off < 16; off <<= 1)
                rsum[r] += __shfl_xor(rsum[r], off, 64);
            lrow[r] += rsum[r];
        }

        // ---- P -> per-wave LDS (C-layout -> A-layout round trip; same-wave, no barrier)
        #pragma unroll
        for (int r = 0; r < 4; ++r)
            #pragma unroll
            for (int n = 0; n < 4; ++n)
                p_sh[wave][(lhi * 4 + r) * LDT + n * 16 + l15] = (__bf16)sf[n][r];

        // ---- ctx += P V ----
        #pragma unroll
        for (int ks = 0; ks < 2; ++ks) {
            bf16x8_t pa = *(const bf16x8_t*)(&p_sh[wave][l15 * LDT + ks * 32 + lhi * 8]);
            #pragma unroll
            for (int n = 0; n < 4; ++n) {
                bf16x8_t vf = *(const bf16x8_t*)(vt_sh + (n * 16 + l15) * LDT + ks * 32 + lhi * 8);
                acc[n] = MFMA16(pa, vf, acc[n]);
            }
        }
    }

    // ---- epilogue: normalize and store ctx in [B*S, DMODEL] bf16 layout ----
    __bf16* Ob = Om + (size_t)b * SEQ * DMODEL + h * DK;
    #pragma unroll
    for (int n = 0; n < 4; ++n)
        #pragma unroll
        for (int r = 0; r < 4; ++r) {
            int row = q0 + wave * 16 + lhi * 4 + r;
            Ob[(size_t)row * DMODEL + n * 16 + l15] = (__bf16)(acc[n][r] / lrow[r]);
        }
}

// ================= launch ============================================================
extern "C" void kernel_launch(void* const* d_in, const int* in_sizes, int n_in,
                              void* d_out, int out_size, void* d_ws, size_t ws_size,
                              hipStream_t stream)
{
    const float* q  = (const float*)d_in[0];
    const float* k  = (const float*)d_in[1];
    const float* v  = (const float*)d_in[2];
    // d_in[3] = causal tril mask (int32) — applied analytically
    const float* wq = (const float*)d_in[4];
    const float* wk = (const float*)d_in[5];
    const float* wv = (const float*)d_in[6];
    const float* wo = (const float*)d_in[7];
    float* out = (float*)d_out;

    const size_t mat = (size_t)MTOT * DMODEL;  // 4096*1024 elements
    __bf16* Qw = (__bf16*)d_ws;                // bf16 workspace: Q,K,V,ctx = 32 MB
    __bf16* Kw = Qw + mat;
    __bf16* Vw = Kw + mat;
    __bf16* Cw = Vw + mat;

    dim3 blk(256);
    proj_qkv_kernel<<<dim3(DMODEL / 128, MTOT / 128, 3), blk, 0, stream>>>(
        q, k, v, wq, wk, wv, Qw, Kw, Vw);
    attn_kernel<<<dim3(SEQ / 64, BATCH * NHEAD), blk, 0, stream>>>(Qw, Kw, Vw, Cw);
    proj_out_kernel<<<dim3(DMODEL / 128, MTOT / 128), blk, 0, stream>>>(Cw, wo, out);
}

// Round 3
// 251.585 us; speedup vs baseline: 1.0633x; 1.0633x over previous
//
#include <hip/hip_runtime.h>
#include <hip/hip_bf16.h>

using bf16x8_t = __attribute__((ext_vector_type(8))) __bf16;
using f32x4_t  = __attribute__((ext_vector_type(4))) float;

#define MFMA16(a, b, c) __builtin_amdgcn_mfma_f32_16x16x32_bf16((a), (b), (c), 0, 0, 0)

constexpr int BATCH   = 2;
constexpr int SEQ     = 2048;
constexpr int DMODEL  = 1024;
constexpr int DK      = 64;
constexpr int MTOT    = BATCH * SEQ;
constexpr float SM_SCALE = 0.125f;

// ---- async global->LDS, 16B per lane; dest = wave-uniform base + lane*16 (m104) ----
typedef const __attribute__((address_space(1))) unsigned int ga_u32;
typedef __attribute__((address_space(3))) unsigned int ls_u32;
__device__ __forceinline__ void glds16(const void* g, void* l) {
    __builtin_amdgcn_global_load_lds((ga_u32*)g, (ls_u32*)l, 16, 0, 0);
}

// pack 8 fp32 (two swizzled 16B chunks of an LDS row) -> bf16x8 fragment
__device__ __forceinline__ bf16x8_t pack_row_frag(const float* row_base, int row, int lhi) {
    f32x4_t v0 = *(const f32x4_t*)(row_base + ((lhi * 2 + 0) ^ (row & 7)) * 4);
    f32x4_t v1 = *(const f32x4_t*)(row_base + ((lhi * 2 + 1) ^ (row & 7)) * 4);
    bf16x8_t r;
    r[0] = (__bf16)v0[0]; r[1] = (__bf16)v0[1]; r[2] = (__bf16)v0[2]; r[3] = (__bf16)v0[3];
    r[4] = (__bf16)v1[0]; r[5] = (__bf16)v1[1]; r[6] = (__bf16)v1[2]; r[7] = (__bf16)v1[3];
    return r;
}

// ================= GEMM: C[M,N] = A[M,K] * Bt[N,K]^T ================================
// 128x128 tile, BK=32, 4 waves (2x2). Operands staged with global_load_lds:
//  - fp32 operand: LDS [128][32] f32 linear dest, chunk-swizzled (col^ = row&7) via
//    pre-swizzled SOURCE address (rule #21); read with same XOR -> uniform banks.
//  - bf16 operand (A of out-proj): LDS [128][32] bf16 linear, 64B rows = conflict-free.
template<bool A_BF16, bool C_F32>
__device__ __forceinline__ void gemm_body(
    const void* __restrict__ Ap, const float* __restrict__ Bt,
    void* __restrict__ Cp, int m0, int n0)
{
    constexpr int K = DMODEL, N = DMODEL;
    constexpr int A_LS_BYTES = A_BF16 ? 8192 : 16384;
    __shared__ __align__(16) char smem[A_LS_BYTES + 16384];
    char*  a_ls = smem;
    float* b_ls = (float*)(smem + A_LS_BYTES);

    const int tid  = threadIdx.x;
    const int wave = tid >> 6, lane = tid & 63;
    const int wm = wave >> 1, wn = wave & 1;
    const int l15 = lane & 15, lhi = lane >> 4;

    f32x4_t acc[4][4] = {};

    for (int k0 = 0; k0 < K; k0 += 32) {
        __syncthreads();
        // ---- stage A ----
        if constexpr (A_BF16) {
            const __bf16* Ab = (const __bf16*)Ap;
            #pragma unroll
            for (int i = 0; i < 2; ++i) {
                int cbase = wave * 128 + i * 64;
                int c = cbase + lane;
                int row = c >> 2, col = c & 3;                 // linear, no swizzle
                glds16(Ab + (size_t)(m0 + row) * K + k0 + col * 8, a_ls + (size_t)cbase * 16);
            }
        } else {
            const float* Af = (const float*)Ap;
            #pragma unroll
            for (int i = 0; i < 4; ++i) {
                int cbase = wave * 256 + i * 64;
                int c = cbase + lane;
                int row = c >> 3, col = (c & 7) ^ (row & 7);   // inverse-swizzled source
                glds16(Af + (size_t)(m0 + row) * K + k0 + col * 4, a_ls + (size_t)cbase * 16);
            }
        }
        // ---- stage B (fp32, swizzled) ----
        #pragma unroll
        for (int i = 0; i < 4; ++i) {
            int cbase = wave * 256 + i * 64;
            int c = cbase + lane;
            int row = c >> 3, col = (c & 7) ^ (row & 7);
            glds16(Bt + (size_t)(n0 + row) * K + k0 + col * 4, (char*)b_ls + (size_t)cbase * 16);
        }
        __syncthreads();   // drains vmcnt -> staged data visible

        bf16x8_t af[4], bfr[4];
        #pragma unroll
        for (int i = 0; i < 4; ++i) {
            int row = wm * 64 + i * 16 + l15;
            if constexpr (A_BF16)
                af[i] = *(const bf16x8_t*)((const __bf16*)a_ls + row * 32 + lhi * 8);
            else
                af[i] = pack_row_frag((const float*)a_ls + row * 32, row, lhi);
        }
        #pragma unroll
        for (int j = 0; j < 4; ++j) {
            int row = wn * 64 + j * 16 + l15;
            bfr[j] = pack_row_frag(b_ls + row * 32, row, lhi);
        }
        #pragma unroll
        for (int i = 0; i < 4; ++i)
            #pragma unroll
            for (int j = 0; j < 4; ++j)
                acc[i][j] = MFMA16(af[i], bfr[j], acc[i][j]);
    }

    // C/D layout (m89): col = lane&15, row = (lane>>4)*4 + reg
    #pragma unroll
    for (int i = 0; i < 4; ++i)
        #pragma unroll
        for (int j = 0; j < 4; ++j)
            #pragma unroll
            for (int r = 0; r < 4; ++r) {
                int row = m0 + wm * 64 + i * 16 + lhi * 4 + r;
                int col = n0 + wn * 64 + j * 16 + l15;
                if constexpr (C_F32)
                    ((float*)Cp)[(size_t)row * N + col] = acc[i][j][r];
                else
                    ((__bf16*)Cp)[(size_t)row * N + col] = (__bf16)acc[i][j][r];
            }
}

__global__ __launch_bounds__(256) void proj_qkv_kernel(
    const float* __restrict__ xq, const float* __restrict__ xk, const float* __restrict__ xv,
    const float* __restrict__ wq, const float* __restrict__ wk, const float* __restrict__ wv,
    __bf16* __restrict__ oq, __bf16* __restrict__ ok, __bf16* __restrict__ ov)
{
    const float* A; const float* Bt; __bf16* C;
    if (blockIdx.z == 0)      { A = xq; Bt = wq; C = oq; }
    else if (blockIdx.z == 1) { A = xk; Bt = wk; C = ok; }
    else                      { A = xv; Bt = wv; C = ov; }
    gemm_body<false, false>(A, Bt, C, blockIdx.y * 128, blockIdx.x * 128);
}

__global__ __launch_bounds__(256) void proj_out_kernel(
    const __bf16* __restrict__ ctx, const float* __restrict__ wo, float* __restrict__ out)
{
    gemm_body<true, true>(ctx, wo, out, blockIdx.y * 128, blockIdx.x * 128);
}

// ================= Flash attention (causal) ==========================================
// grid (SEQ/128, B*H), 256 threads = 4 waves; wave owns 32 q-rows (two 16-row blocks).
// K: row-major LDS [64][72] (padded). V: kv-rotated layout, element (d,kv) at
// d*64 + ((kv + 8*(d>>3)) & 63)  -> conflict-free scalar stores AND aligned b128 reads.
// P: per-wave LDS with the same rotation keyed on q.
__global__ __launch_bounds__(256) void attn_kernel(
    const __bf16* __restrict__ Qm, const __bf16* __restrict__ Km,
    const __bf16* __restrict__ Vm, __bf16* __restrict__ Om)
{
    constexpr int LDK = 72;
    __shared__ __bf16 k_sh[64 * LDK];
    __shared__ __bf16 v_sh[64 * 64];
    __shared__ __bf16 p_sh[4][16 * LDK];

    const int tid  = threadIdx.x;
    const int wave = tid >> 6, lane = tid & 63;
    const int l15 = lane & 15, lhi = lane >> 4;

    const int q0 = blockIdx.x * 128;
    const int b = blockIdx.y >> 4, h = blockIdx.y & 15;

    const __bf16* Qb = Qm + (size_t)b * SEQ * DMODEL + h * DK;
    const __bf16* Kb = Km + (size_t)b * SEQ * DMODEL + h * DK;
    const __bf16* Vb = Vm + (size_t)b * SEQ * DMODEL + h * DK;

    const int wq0 = q0 + wave * 32;

    bf16x8_t qf[2][2];
    #pragma unroll
    for (int qb = 0; qb < 2; ++qb) {
        const __bf16* qp = Qb + (size_t)(wq0 + qb * 16 + l15) * DMODEL + lhi * 8;
        qf[qb][0] = *(const bf16x8_t*)qp;
        qf[qb][1] = *(const bf16x8_t*)(qp + 32);
    }

    f32x4_t acc[2][4] = {};
    float mrow[2][4], lrow[2][4];
    #pragma unroll
    for (int qb = 0; qb < 2; ++qb)
        #pragma unroll
        for (int r = 0; r < 4; ++r) { mrow[qb][r] = -INFINITY; lrow[qb][r] = 0.f; }

    const int ntiles = 2 * blockIdx.x + 2;
    for (int t = 0; t < ntiles; ++t) {
        const int kv0 = t * 64;
        __syncthreads();
        #pragma unroll
        for (int s = 0; s < 2; ++s) {
            int slot = tid + s * 256;
            int row = slot >> 3, grp = slot & 7;
            bf16x8_t kv8 = *(const bf16x8_t*)(Kb + (size_t)(kv0 + row) * DMODEL + grp * 8);
            *(bf16x8_t*)(k_sh + row * LDK + grp * 8) = kv8;
            bf16x8_t vv8 = *(const bf16x8_t*)(Vb + (size_t)(kv0 + row) * DMODEL + grp * 8);
            int sh = (row + grp * 8) & 63;       // rotation: d>>3 == grp for all 8 j
            #pragma unroll
            for (int j = 0; j < 8; ++j)
                v_sh[(grp * 8 + j) * 64 + sh] = vv8[j];
        }
        __syncthreads();

        #pragma unroll
        for (int qb = 0; qb < 2; ++qb) {
            const int qbase = wq0 + qb * 16;
            if (kv0 >= qbase + 16) continue;     // fully-masked block: skip

            // ---- S = Q K^T ----
            f32x4_t sf[4] = {};
            #pragma unroll
            for (int ks = 0; ks < 2; ++ks)
                #pragma unroll
                for (int n = 0; n < 4; ++n) {
                    bf16x8_t kf = *(const bf16x8_t*)(k_sh + (n * 16 + l15) * LDK + ks * 32 + lhi * 8);
                    sf[n] = MFMA16(qf[qb][ks], kf, sf[n]);
                }

            // ---- scale + (conditional) causal mask + online softmax ----
            const bool needmask = (kv0 + 63) > qbase;
            const int qrow_base = qbase + lhi * 4;
            float pmax[4];
            #pragma unroll
            for (int r = 0; r < 4; ++r) {
                float mx = -3.0e38f;
                #pragma unroll
                for (int n = 0; n < 4; ++n) {
                    float sv = sf[n][r] * SM_SCALE;
                    if (needmask && (kv0 + n * 16 + l15 > qrow_base + r)) sv = -1.0e30f;
                    sf[n][r] = sv;
                    mx = fmaxf(mx, sv);
                }
                pmax[r] = mx;
            }
            #pragma unroll
            for (int r = 0; r < 4; ++r)
                #pragma unroll
                for (int off = 1; off < 16; off <<= 1)
                    pmax[r] = fmaxf(pmax[r], __shfl_xor(pmax[r], off, 64));

            float rsum[4];
            #pragma unroll
            for (int r = 0; r < 4; ++r) {
                float mnew = fmaxf(mrow[qb][r], pmax[r]);
                float sfac = __expf(mrow[qb][r] - mnew);
                mrow[qb][r] = mnew;
                float rs = 0.f;
                #pragma unroll
                for (int n = 0; n < 4; ++n) {
                    float p = __expf(sf[n][r] - mnew);
                    sf[n][r] = p;
                    rs += p;
                }
                rsum[r] = rs;
                lrow[qb][r] *= sfac;
                #pragma unroll
                for (int n = 0; n < 4; ++n) acc[qb][n][r] *= sfac;
            }
            #pragma unroll
            for (int r = 0; r < 4; ++r) {
                #pragma unroll
                for (int off = 1; off < 16; off <<= 1)
                    rsum[r] += __shfl_xor(rsum[r], off, 64);
                lrow[qb][r] += rsum[r];
            }

            // ---- P -> per-wave LDS (rotated), same-wave in-order, no barrier ----
            #pragma unroll
            for (int r = 0; r < 4; ++r)
                #pragma unroll
                for (int n = 0; n < 4; ++n)
                    p_sh[wave][(lhi * 4 + r) * LDK + ((n * 16 + l15 + ((lhi >> 1) << 3)) & 63)]
                        = (__bf16)sf[n][r];

            // ---- ctx += P V ----
            #pragma unroll
            for (int ks = 0; ks < 2; ++ks) {
                bf16x8_t pa = *(const bf16x8_t*)(
                    &p_sh[wave][l15 * LDK + ((ks * 32 + lhi * 8 + ((l15 >> 3) << 3)) & 63)]);
                #pragma unroll
                for (int n = 0; n < 4; ++n) {
                    int d = n * 16 + l15;
                    int sh = (ks * 32 + lhi * 8 + ((d >> 3) << 3)) & 63;
                    bf16x8_t vf = *(const bf16x8_t*)(v_sh + d * 64 + sh);
                    acc[qb][n] = MFMA16(pa, vf, acc[qb][n]);
                }
            }
        }
    }

    // ---- epilogue ----
    __bf16* Ob = Om + (size_t)b * SEQ * DMODEL + h * DK;
    #pragma unroll
    for (int qb = 0; qb < 2; ++qb)
        #pragma unroll
        for (int n = 0; n < 4; ++n)
            #pragma unroll
            for (int r = 0; r < 4; ++r) {
                int row = wq0 + qb * 16 + lhi * 4 + r;
                Ob[(size_t)row * DMODEL + n * 16 + l15] = (__bf16)(acc[qb][n][r] / lrow[qb][r]);
            }
}

// ================= launch ============================================================
extern "C" void kernel_launch(void* const* d_in, const int* in_sizes, int n_in,
                              void* d_out, int out_size, void* d_ws, size_t ws_size,
                              hipStream_t stream)
{
    const float* q  = (const float*)d_in[0];
    const float* k  = (const float*)d_in[1];
    const float* v  = (const float*)d_in[2];
    const float* wq = (const float*)d_in[4];
    const float* wk = (const float*)d_in[5];
    const float* wv = (const float*)d_in[6];
    const float* wo = (const float*)d_in[7];
    float* out = (float*)d_out;

    const size_t mat = (size_t)MTOT * DMODEL;
    __bf16* Qw = (__bf16*)d_ws;
    __bf16* Kw = Qw + mat;
    __bf16* Vw = Kw + mat;
    __bf16* Cw = Vw + mat;

    dim3 blk(256);
    proj_qkv_kernel<<<dim3(DMODEL / 128, MTOT / 128, 3), blk, 0, stream>>>(
        q, k, v, wq, wk, wv, Qw, Kw, Vw);
    attn_kernel<<<dim3(SEQ / 128, BATCH * 16), blk, 0, stream>>>(Qw, Kw, Vw, Cw);
    proj_out_kernel<<<dim3(DMODEL / 128, MTOT / 128), blk, 0, stream>>>(Cw, wo, out);
}

// Round 4
// 183.156 us; speedup vs baseline: 1.4606x; 1.3736x over previous
//
#include <hip/hip_runtime.h>
#include <hip/hip_bf16.h>

using bf16x8_t = __attribute__((ext_vector_type(8))) __bf16;
using f32x4_t  = __attribute__((ext_vector_type(4))) float;

#define MFMA16(a, b, c) __builtin_amdgcn_mfma_f32_16x16x32_bf16((a), (b), (c), 0, 0, 0)

constexpr int BATCH   = 2;
constexpr int SEQ     = 2048;
constexpr int DMODEL  = 1024;
constexpr int DK      = 64;
constexpr int MTOT    = BATCH * SEQ;
constexpr float SM_SCALE = 0.125f;

// ---- async global->LDS, 16B/lane; dest = wave-uniform base + lane*16 (m104) ----
typedef const __attribute__((address_space(1))) unsigned int ga_u32;
typedef __attribute__((address_space(3))) unsigned int ls_u32;
__device__ __forceinline__ void glds16(const void* g, void* l) {
    __builtin_amdgcn_global_load_lds((ga_u32*)g, (ls_u32*)l, 16, 0, 0);
}

__device__ __forceinline__ bf16x8_t cvt8(const float* __restrict__ p) {
    f32x4_t a = *(const f32x4_t*)p;
    f32x4_t b = *(const f32x4_t*)(p + 4);
    bf16x8_t r;
    r[0] = (__bf16)a[0]; r[1] = (__bf16)a[1]; r[2] = (__bf16)a[2]; r[3] = (__bf16)a[3];
    r[4] = (__bf16)b[0]; r[5] = (__bf16)b[1]; r[6] = (__bf16)b[2]; r[7] = (__bf16)b[3];
    return r;
}

// pack 8 fp32 (two xor-swizzled 16B chunks of a 128B LDS row) -> bf16x8 fragment
__device__ __forceinline__ bf16x8_t pack_row_frag(const float* row_base, int row, int lhi) {
    f32x4_t v0 = *(const f32x4_t*)(row_base + ((lhi * 2 + 0) ^ (row & 7)) * 4);
    f32x4_t v1 = *(const f32x4_t*)(row_base + ((lhi * 2 + 1) ^ (row & 7)) * 4);
    bf16x8_t r;
    r[0] = (__bf16)v0[0]; r[1] = (__bf16)v0[1]; r[2] = (__bf16)v0[2]; r[3] = (__bf16)v0[3];
    r[4] = (__bf16)v1[0]; r[5] = (__bf16)v1[1]; r[6] = (__bf16)v1[2]; r[7] = (__bf16)v1[3];
    return r;
}

// ---- weight fp32 -> bf16 convert: grid (512, 4), 256 thr, 8 elems/thread ----
__global__ __launch_bounds__(256) void cvt_w_kernel(
    const float* __restrict__ w0, const float* __restrict__ w1,
    const float* __restrict__ w2, const float* __restrict__ w3, __bf16* __restrict__ dst)
{
    const float* srcs[4] = {w0, w1, w2, w3};
    const float* s = srcs[blockIdx.y];
    __bf16* d = dst + (size_t)blockIdx.y * (DMODEL * DMODEL);
    size_t i = ((size_t)blockIdx.x * 256 + threadIdx.x) * 8;
    *(bf16x8_t*)(d + i) = cvt8(s + i);
}

// ================= GEMM: C[M,N] = A[M,K] * Bt[N,K]^T ================================
// 128x128 tile, BK=32, 4 waves (2x2), all staging via global_load_lds.
//  - fp32 A: LDS [128][32]f32 linear, 8 chunks/row, chunk c stored at c^(row&7).
//  - bf16 A/B: LDS [128][32]bf16, 4 chunks/row, global chunk g stored at (g+(row>>1))&3
//    (add-rotate): read banks 2-way aliased only (free).
template<bool A_BF16, bool C_F32>
__device__ __forceinline__ void gemm_body(
    const void* __restrict__ Ap, const __bf16* __restrict__ Bt,
    void* __restrict__ Cp, int m0, int n0)
{
    constexpr int K = DMODEL, N = DMODEL;
    constexpr int A_LS_BYTES = A_BF16 ? 8192 : 16384;
    __shared__ __align__(16) char smem[A_LS_BYTES + 8192];
    char*   a_ls = smem;
    __bf16* b_ls = (__bf16*)(smem + A_LS_BYTES);

    const int tid  = threadIdx.x;
    const int wave = tid >> 6, lane = tid & 63;
    const int wm = wave >> 1, wn = wave & 1;
    const int l15 = lane & 15, lhi = lane >> 4;

    f32x4_t acc[4][4] = {};

    for (int k0 = 0; k0 < K; k0 += 32) {
        __syncthreads();
        // ---- stage A ----
        if constexpr (A_BF16) {
            const __bf16* Ab = (const __bf16*)Ap;
            #pragma unroll
            for (int i = 0; i < 2; ++i) {
                int cbase = i * 256 + wave * 64;
                int slot = cbase + lane;
                int row = slot >> 2, c = slot & 3;
                int cs = (c + 4 - ((row >> 1) & 3)) & 3;
                glds16(Ab + (size_t)(m0 + row) * K + k0 + cs * 8, a_ls + (size_t)cbase * 16);
            }
        } else {
            const float* Af = (const float*)Ap;
            #pragma unroll
            for (int i = 0; i < 4; ++i) {
                int cbase = i * 256 + wave * 64;
                int slot = cbase + lane;
                int row = slot >> 3, c = (slot & 7) ^ (row & 7);
                glds16(Af + (size_t)(m0 + row) * K + k0 + c * 4, a_ls + (size_t)cbase * 16);
            }
        }
        // ---- stage B (bf16) ----
        #pragma unroll
        for (int i = 0; i < 2; ++i) {
            int cbase = i * 256 + wave * 64;
            int slot = cbase + lane;
            int row = slot >> 2, c = slot & 3;
            int cs = (c + 4 - ((row >> 1) & 3)) & 3;
            glds16(Bt + (size_t)(n0 + row) * K + k0 + cs * 8, (char*)b_ls + (size_t)cbase * 16);
        }
        __syncthreads();   // drains vmcnt -> staged data visible

        bf16x8_t af[4], bfr[4];
        #pragma unroll
        for (int i = 0; i < 4; ++i) {
            int row = wm * 64 + i * 16 + l15;
            if constexpr (A_BF16) {
                int lc = (lhi + (row >> 1)) & 3;
                af[i] = *(const bf16x8_t*)((const __bf16*)a_ls + row * 32 + lc * 8);
            } else {
                af[i] = pack_row_frag((const float*)a_ls + row * 32, row, lhi);
            }
        }
        #pragma unroll
        for (int j = 0; j < 4; ++j) {
            int row = wn * 64 + j * 16 + l15;
            int lc = (lhi + (row >> 1)) & 3;
            bfr[j] = *(const bf16x8_t*)(b_ls + row * 32 + lc * 8);
        }
        #pragma unroll
        for (int i = 0; i < 4; ++i)
            #pragma unroll
            for (int j = 0; j < 4; ++j)
                acc[i][j] = MFMA16(af[i], bfr[j], acc[i][j]);
    }

    // C/D layout (m89): col = lane&15, row = (lane>>4)*4 + reg
    #pragma unroll
    for (int i = 0; i < 4; ++i)
        #pragma unroll
        for (int j = 0; j < 4; ++j)
            #pragma unroll
            for (int r = 0; r < 4; ++r) {
                int row = m0 + wm * 64 + i * 16 + lhi * 4 + r;
                int col = n0 + wn * 64 + j * 16 + l15;
                if constexpr (C_F32)
                    ((float*)Cp)[(size_t)row * N + col] = acc[i][j][r];
                else
                    ((__bf16*)Cp)[(size_t)row * N + col] = (__bf16)acc[i][j][r];
            }
}

__global__ __launch_bounds__(256) void proj_qkv_kernel(
    const float* __restrict__ xq, const float* __restrict__ xk, const float* __restrict__ xv,
    const __bf16* __restrict__ wc,
    __bf16* __restrict__ oq, __bf16* __restrict__ ok, __bf16* __restrict__ ov)
{
    const float* A; const __bf16* Bt; __bf16* C;
    if (blockIdx.z == 0)      { A = xq; Bt = wc;                   C = oq; }
    else if (blockIdx.z == 1) { A = xk; Bt = wc + DMODEL * DMODEL; C = ok; }
    else                      { A = xv; Bt = wc + 2 * DMODEL * DMODEL; C = ov; }
    gemm_body<false, false>(A, Bt, C, blockIdx.y * 128, blockIdx.x * 128);
}

__global__ __launch_bounds__(256) void proj_out_kernel(
    const __bf16* __restrict__ ctx, const __bf16* __restrict__ woc, float* __restrict__ out)
{
    gemm_body<true, true>(ctx, woc, out, blockIdx.y * 128, blockIdx.x * 128);
}

// ================= Flash attention (causal, pair-balanced) ===========================
// grid (16, 32). Block handles q-tiles p and 31-p (64 rows each, QBLK=64), streaming
// KV tiles 0..(31-p) once; both q-tiles consume the shared staged K/V while active.
// p = (y<16) ? x : 15-x so co-resident blocks (d, d+256) have uniform stage counts.
// K: LDS [64][64] via glds16, chunk xor-swizzle (c^(row&7)). V: rotated layout,
// (d,kv) at d*64 + ((kv + 8*(d>>3))&63). P: per-wave [16][72] rotated (as R2).
__global__ __launch_bounds__(256) void attn_kernel(
    const __bf16* __restrict__ Qm, const __bf16* __restrict__ Km,
    const __bf16* __restrict__ Vm, __bf16* __restrict__ Om)
{
    constexpr int LDP = 72;
    __shared__ __bf16 k_sh[64 * 64];
    __shared__ __bf16 v_sh[64 * 64];
    __shared__ __bf16 p_sh[4][16 * LDP];

    const int tid  = threadIdx.x;
    const int wave = tid >> 6, lane = tid & 63;
    const int l15 = lane & 15, lhi = lane >> 4;

    const int x = blockIdx.x, y = blockIdx.y;
    const int p = (y < 16) ? x : 15 - x;
    const int tileA = p, tileB = 31 - p;
    const int b = y >> 4, h = y & 15;

    const __bf16* Qb = Qm + (size_t)b * SEQ * DMODEL + h * DK;
    const __bf16* Kb = Km + (size_t)b * SEQ * DMODEL + h * DK;
    const __bf16* Vb = Vm + (size_t)b * SEQ * DMODEL + h * DK;

    // Q fragments (A layout: row = lane&15, k = (lane>>4)*8 + j)
    bf16x8_t qfA[2], qfB[2];
    {
        const __bf16* qa = Qb + (size_t)(tileA * 64 + wave * 16 + l15) * DMODEL + lhi * 8;
        qfA[0] = *(const bf16x8_t*)qa;  qfA[1] = *(const bf16x8_t*)(qa + 32);
        const __bf16* qb = Qb + (size_t)(tileB * 64 + wave * 16 + l15) * DMODEL + lhi * 8;
        qfB[0] = *(const bf16x8_t*)qb;  qfB[1] = *(const bf16x8_t*)(qb + 32);
    }

    f32x4_t accA[4] = {}, accB[4] = {};
    float mA[4], lA[4], mB[4], lB[4];
    #pragma unroll
    for (int r = 0; r < 4; ++r) { mA[r] = -INFINITY; lA[r] = 0.f; mB[r] = -INFINITY; lB[r] = 0.f; }

    auto tile_body = [&](const bf16x8_t (&qf)[2], f32x4_t (&acc)[4], float (&m)[4],
                         float (&l)[4], int qbase, bool needmask, int kv0) {
        // ---- S = Q K^T ----
        f32x4_t sf[4] = {};
        #pragma unroll
        for (int ks = 0; ks < 2; ++ks)
            #pragma unroll
            for (int n = 0; n < 4; ++n) {
                int row = n * 16 + l15;
                bf16x8_t kf = *(const bf16x8_t*)(k_sh + row * 64 + (((ks * 4 + lhi) ^ (row & 7)) * 8));
                sf[n] = MFMA16(qf[ks], kf, sf[n]);
            }

        // ---- scale + (conditional) mask + online softmax ----
        const int qrow_base = qbase + lhi * 4;
        float pmax[4];
        #pragma unroll
        for (int r = 0; r < 4; ++r) {
            float mx = -3.0e38f;
            #pragma unroll
            for (int n = 0; n < 4; ++n) {
                float sv = sf[n][r] * SM_SCALE;
                if (needmask && (kv0 + n * 16 + l15 > qrow_base + r)) sv = -1.0e30f;
                sf[n][r] = sv;
                mx = fmaxf(mx, sv);
            }
            pmax[r] = mx;
        }
        #pragma unroll
        for (int r = 0; r < 4; ++r)
            #pragma unroll
            for (int off = 1; off < 16; off <<= 1)
                pmax[r] = fmaxf(pmax[r], __shfl_xor(pmax[r], off, 64));

        float rsum[4];
        #pragma unroll
        for (int r = 0; r < 4; ++r) {
            float mnew = fmaxf(m[r], pmax[r]);
            float sfac = __expf(m[r] - mnew);
            m[r] = mnew;
            float rs = 0.f;
            #pragma unroll
            for (int n = 0; n < 4; ++n) {
                float pv = __expf(sf[n][r] - mnew);
                sf[n][r] = pv;
                rs += pv;
            }
            rsum[r] = rs;
            l[r] *= sfac;
            #pragma unroll
            for (int n = 0; n < 4; ++n) acc[n][r] *= sfac;
        }
        #pragma unroll
        for (int r = 0; r < 4; ++r) {
            #pragma unroll
            for (int off = 1; off < 16; off <<= 1)
                rsum[r] += __shfl_xor(rsum[r], off, 64);
            l[r] += rsum[r];
        }

        // ---- P -> per-wave rotated LDS (same-wave in-order, no barrier) ----
        #pragma unroll
        for (int r = 0; r < 4; ++r)
            #pragma unroll
            for (int n = 0; n < 4; ++n)
                p_sh[wave][(lhi * 4 + r) * LDP + ((n * 16 + l15 + ((lhi >> 1) << 3)) & 63)]
                    = (__bf16)sf[n][r];

        // ---- ctx += P V ----
        #pragma unroll
        for (int ks = 0; ks < 2; ++ks) {
            bf16x8_t pa = *(const bf16x8_t*)(
                &p_sh[wave][l15 * LDP + ((ks * 32 + lhi * 8 + ((l15 >> 3) << 3)) & 63)]);
            #pragma unroll
            for (int n = 0; n < 4; ++n) {
                int d = n * 16 + l15;
                int sh = (ks * 32 + lhi * 8 + ((d >> 3) << 3)) & 63;
                bf16x8_t vf = *(const bf16x8_t*)(v_sh + d * 64 + sh);
                acc[n] = MFMA16(pa, vf, acc[n]);
            }
        }
    };

    const int Tmax = tileB + 1;
    for (int t = 0; t < Tmax; ++t) {
        const int kv0 = t * 64;
        __syncthreads();
        // ---- stage K via glds16 (xor-swizzled source, linear dest) ----
        #pragma unroll
        for (int i = 0; i < 2; ++i) {
            int cbase = i * 256 + wave * 64;
            int slot = cbase + lane;
            int row = slot >> 3, c = (slot & 7) ^ (row & 7);
            glds16(Kb + (size_t)(kv0 + row) * DMODEL + c * 8, (char*)k_sh + (size_t)cbase * 16);
        }
        // ---- stage V rotated (scalar stores, 1 word/bank) ----
        #pragma unroll
        for (int s = 0; s < 2; ++s) {
            int slot = tid + s * 256;
            int row = slot >> 3, grp = slot & 7;
            bf16x8_t vv8 = *(const bf16x8_t*)(Vb + (size_t)(kv0 + row) * DMODEL + grp * 8);
            int sh = (row + grp * 8) & 63;
            #pragma unroll
            for (int j = 0; j < 8; ++j)
                v_sh[(grp * 8 + j) * 64 + sh] = vv8[j];
        }
        __syncthreads();

        if (t <= tileA)
            tile_body(qfA, accA, mA, lA, tileA * 64 + wave * 16, t == tileA, kv0);
        tile_body(qfB, accB, mB, lB, tileB * 64 + wave * 16, t == tileB, kv0);
    }

    // ---- epilogue ----
    __bf16* Ob = Om + (size_t)b * SEQ * DMODEL + h * DK;
    #pragma unroll
    for (int n = 0; n < 4; ++n)
        #pragma unroll
        for (int r = 0; r < 4; ++r) {
            int rowA = tileA * 64 + wave * 16 + lhi * 4 + r;
            Ob[(size_t)rowA * DMODEL + n * 16 + l15] = (__bf16)(accA[n][r] / lA[r]);
            int rowB = tileB * 64 + wave * 16 + lhi * 4 + r;
            Ob[(size_t)rowB * DMODEL + n * 16 + l15] = (__bf16)(accB[n][r] / lB[r]);
        }
}

// ================= launch ============================================================
extern "C" void kernel_launch(void* const* d_in, const int* in_sizes, int n_in,
                              void* d_out, int out_size, void* d_ws, size_t ws_size,
                              hipStream_t stream)
{
    const float* q  = (const float*)d_in[0];
    const float* k  = (const float*)d_in[1];
    const float* v  = (const float*)d_in[2];
    const float* wq = (const float*)d_in[4];
    const float* wk = (const float*)d_in[5];
    const float* wv = (const float*)d_in[6];
    const float* wo = (const float*)d_in[7];
    float* out = (float*)d_out;

    const size_t mat = (size_t)MTOT * DMODEL;   // 4M elems
    __bf16* Qw = (__bf16*)d_ws;                 // 8 MB each
    __bf16* Kw = Qw + mat;
    __bf16* Vw = Kw + mat;
    __bf16* Cw = Vw + mat;
    __bf16* Wc = Cw + mat;                      // 4 x 2 MB bf16 weights (wq,wk,wv,wo)

    dim3 blk(256);
    cvt_w_kernel<<<dim3(512, 4), blk, 0, stream>>>(wq, wk, wv, wo, Wc);
    proj_qkv_kernel<<<dim3(DMODEL / 128, MTOT / 128, 3), blk, 0, stream>>>(
        q, k, v, Wc, Qw, Kw, Vw);
    attn_kernel<<<dim3(16, 32), blk, 0, stream>>>(Qw, Kw, Vw, Cw);
    proj_out_kernel<<<dim3(DMODEL / 128, MTOT / 128), blk, 0, stream>>>(
        Cw, Wc + 3 * DMODEL * DMODEL, out);
}

// Round 5
// 179.457 us; speedup vs baseline: 1.4907x; 1.0206x over previous
//
#include <hip/hip_runtime.h>
#include <hip/hip_bf16.h>

using bf16x8_t = __attribute__((ext_vector_type(8))) __bf16;
using f32x4_t  = __attribute__((ext_vector_type(4))) float;

#define MFMA16(a, b, c) __builtin_amdgcn_mfma_f32_16x16x32_bf16((a), (b), (c), 0, 0, 0)

constexpr int BATCH   = 2;
constexpr int SEQ     = 2048;
constexpr int DMODEL  = 1024;
constexpr int DK      = 64;
constexpr int MTOT    = BATCH * SEQ;
// softmax in exp2 domain: scores pre-multiplied by 1/sqrt(64) * log2(e)
constexpr float SCL2 = 0.125f * 1.44269504088896f;

// ---- async global->LDS, 16B/lane; dest = wave-uniform base + lane*16 (m104) ----
typedef const __attribute__((address_space(1))) unsigned int ga_u32;
typedef __attribute__((address_space(3))) unsigned int ls_u32;
__device__ __forceinline__ void glds16(const void* g, void* l) {
    __builtin_amdgcn_global_load_lds((ga_u32*)g, (ls_u32*)l, 16, 0, 0);
}

// v_exp_f32 IS exp2
__device__ __forceinline__ float exp2_fast(float x) {
    float r;
    asm volatile("v_exp_f32 %0, %1" : "=v"(r) : "v"(x));
    return r;
}

__device__ __forceinline__ bf16x8_t cvt8(const float* __restrict__ p) {
    f32x4_t a = *(const f32x4_t*)p;
    f32x4_t b = *(const f32x4_t*)(p + 4);
    bf16x8_t r;
    r[0] = (__bf16)a[0]; r[1] = (__bf16)a[1]; r[2] = (__bf16)a[2]; r[3] = (__bf16)a[3];
    r[4] = (__bf16)b[0]; r[5] = (__bf16)b[1]; r[6] = (__bf16)b[2]; r[7] = (__bf16)b[3];
    return r;
}

// pack 8 fp32 (two xor-swizzled 16B chunks of a 128B LDS row) -> bf16x8 fragment
__device__ __forceinline__ bf16x8_t pack_row_frag(const float* row_base, int row, int lhi) {
    f32x4_t v0 = *(const f32x4_t*)(row_base + ((lhi * 2 + 0) ^ (row & 7)) * 4);
    f32x4_t v1 = *(const f32x4_t*)(row_base + ((lhi * 2 + 1) ^ (row & 7)) * 4);
    bf16x8_t r;
    r[0] = (__bf16)v0[0]; r[1] = (__bf16)v0[1]; r[2] = (__bf16)v0[2]; r[3] = (__bf16)v0[3];
    r[4] = (__bf16)v1[0]; r[5] = (__bf16)v1[1]; r[6] = (__bf16)v1[2]; r[7] = (__bf16)v1[3];
    return r;
}

// ---- weight fp32 -> bf16 convert: grid (512, 4), 256 thr, 8 elems/thread ----
__global__ __launch_bounds__(256) void cvt_w_kernel(
    const float* __restrict__ w0, const float* __restrict__ w1,
    const float* __restrict__ w2, const float* __restrict__ w3, __bf16* __restrict__ dst)
{
    const float* srcs[4] = {w0, w1, w2, w3};
    const float* s = srcs[blockIdx.y];
    __bf16* d = dst + (size_t)blockIdx.y * (DMODEL * DMODEL);
    size_t i = ((size_t)blockIdx.x * 256 + threadIdx.x) * 8;
    *(bf16x8_t*)(d + i) = cvt8(s + i);
}

// ================= GEMM: C[M,N] = A[M,K] * Bt[N,K]^T (unchanged from R3) ============
template<bool A_BF16, bool C_F32>
__device__ __forceinline__ void gemm_body(
    const void* __restrict__ Ap, const __bf16* __restrict__ Bt,
    void* __restrict__ Cp, int m0, int n0)
{
    constexpr int K = DMODEL, N = DMODEL;
    constexpr int A_LS_BYTES = A_BF16 ? 8192 : 16384;
    __shared__ __align__(16) char smem[A_LS_BYTES + 8192];
    char*   a_ls = smem;
    __bf16* b_ls = (__bf16*)(smem + A_LS_BYTES);

    const int tid  = threadIdx.x;
    const int wave = tid >> 6, lane = tid & 63;
    const int wm = wave >> 1, wn = wave & 1;
    const int l15 = lane & 15, lhi = lane >> 4;

    f32x4_t acc[4][4] = {};

    for (int k0 = 0; k0 < K; k0 += 32) {
        __syncthreads();
        if constexpr (A_BF16) {
            const __bf16* Ab = (const __bf16*)Ap;
            #pragma unroll
            for (int i = 0; i < 2; ++i) {
                int cbase = i * 256 + wave * 64;
                int slot = cbase + lane;
                int row = slot >> 2, c = slot & 3;
                int cs = (c + 4 - ((row >> 1) & 3)) & 3;
                glds16(Ab + (size_t)(m0 + row) * K + k0 + cs * 8, a_ls + (size_t)cbase * 16);
            }
        } else {
            const float* Af = (const float*)Ap;
            #pragma unroll
            for (int i = 0; i < 4; ++i) {
                int cbase = i * 256 + wave * 64;
                int slot = cbase + lane;
                int row = slot >> 3, c = (slot & 7) ^ (row & 7);
                glds16(Af + (size_t)(m0 + row) * K + k0 + c * 4, a_ls + (size_t)cbase * 16);
            }
        }
        #pragma unroll
        for (int i = 0; i < 2; ++i) {
            int cbase = i * 256 + wave * 64;
            int slot = cbase + lane;
            int row = slot >> 2, c = slot & 3;
            int cs = (c + 4 - ((row >> 1) & 3)) & 3;
            glds16(Bt + (size_t)(n0 + row) * K + k0 + cs * 8, (char*)b_ls + (size_t)cbase * 16);
        }
        __syncthreads();

        bf16x8_t af[4], bfr[4];
        #pragma unroll
        for (int i = 0; i < 4; ++i) {
            int row = wm * 64 + i * 16 + l15;
            if constexpr (A_BF16) {
                int lc = (lhi + (row >> 1)) & 3;
                af[i] = *(const bf16x8_t*)((const __bf16*)a_ls + row * 32 + lc * 8);
            } else {
                af[i] = pack_row_frag((const float*)a_ls + row * 32, row, lhi);
            }
        }
        #pragma unroll
        for (int j = 0; j < 4; ++j) {
            int row = wn * 64 + j * 16 + l15;
            int lc = (lhi + (row >> 1)) & 3;
            bfr[j] = *(const bf16x8_t*)(b_ls + row * 32 + lc * 8);
        }
        #pragma unroll
        for (int i = 0; i < 4; ++i)
            #pragma unroll
            for (int j = 0; j < 4; ++j)
                acc[i][j] = MFMA16(af[i], bfr[j], acc[i][j]);
    }

    #pragma unroll
    for (int i = 0; i < 4; ++i)
        #pragma unroll
        for (int j = 0; j < 4; ++j)
            #pragma unroll
            for (int r = 0; r < 4; ++r) {
                int row = m0 + wm * 64 + i * 16 + lhi * 4 + r;
                int col = n0 + wn * 64 + j * 16 + l15;
                if constexpr (C_F32)
                    ((float*)Cp)[(size_t)row * N + col] = acc[i][j][r];
                else
                    ((__bf16*)Cp)[(size_t)row * N + col] = (__bf16)acc[i][j][r];
            }
}

__global__ __launch_bounds__(256) void proj_qkv_kernel(
    const float* __restrict__ xq, const float* __restrict__ xk, const float* __restrict__ xv,
    const __bf16* __restrict__ wc,
    __bf16* __restrict__ oq, __bf16* __restrict__ ok, __bf16* __restrict__ ov)
{
    const float* A; const __bf16* Bt; __bf16* C;
    if (blockIdx.z == 0)      { A = xq; Bt = wc;                   C = oq; }
    else if (blockIdx.z == 1) { A = xk; Bt = wc + DMODEL * DMODEL; C = ok; }
    else                      { A = xv; Bt = wc + 2 * DMODEL * DMODEL; C = ov; }
    gemm_body<false, false>(A, Bt, C, blockIdx.y * 128, blockIdx.x * 128);
}

__global__ __launch_bounds__(256) void proj_out_kernel(
    const __bf16* __restrict__ ctx, const __bf16* __restrict__ woc, float* __restrict__ out)
{
    gemm_body<true, true>(ctx, woc, out, blockIdx.y * 128, blockIdx.x * 128);
}

// ================= Flash attention (causal, parity-balanced) =========================
// grid (32, 32) = 1024 blocks (4/CU), 256 threads = 4 waves; block owns ONE 64-row
// q-tile at p = ((y>>3)&1) ? 31-x : x  -> co-resident blocks (L, L+256, ...) get
// depths {x, 31-x, x, 31-x}: uniform 66 bodies / 66 stages per CU.
// Softmax in exp2 domain; per-lane l (reduced once at epilogue); rescale skipped by
// wave vote when the running max didn't grow (T13).
__global__ __launch_bounds__(256, 4) void attn_kernel(
    const __bf16* __restrict__ Qm, const __bf16* __restrict__ Km,
    const __bf16* __restrict__ Vm, __bf16* __restrict__ Om)
{
    constexpr int LDP = 72;
    __shared__ __bf16 k_sh[64 * 64];     // glds16, chunk xor-swizzle (c^(row&7))
    __shared__ __bf16 v_sh[64 * 64];     // rotated: (d,kv) at d*64 + ((kv+8*(d>>3))&63)
    __shared__ __bf16 p_sh[4][16 * LDP]; // per-wave, rotated on q>>3

    const int tid  = threadIdx.x;
    const int wave = tid >> 6, lane = tid & 63;
    const int l15 = lane & 15, lhi = lane >> 4;

    const int x = blockIdx.x, y = blockIdx.y;
    const int p = ((y >> 3) & 1) ? 31 - x : x;   // q-tile depth, CU-balanced
    const int q0 = p * 64;
    const int b = y >> 4, h = y & 15;

    const __bf16* Qb = Qm + (size_t)b * SEQ * DMODEL + h * DK;
    const __bf16* Kb = Km + (size_t)b * SEQ * DMODEL + h * DK;
    const __bf16* Vb = Vm + (size_t)b * SEQ * DMODEL + h * DK;

    const int qbase = q0 + wave * 16;

    // Q fragments (A layout: row = lane&15, k = (lane>>4)*8 + j)
    bf16x8_t qf[2];
    {
        const __bf16* qp = Qb + (size_t)(qbase + l15) * DMODEL + lhi * 8;
        qf[0] = *(const bf16x8_t*)qp;
        qf[1] = *(const bf16x8_t*)(qp + 32);
    }

    f32x4_t acc[4] = {};
    float m2[4] = {-INFINITY, -INFINITY, -INFINITY, -INFINITY};
    float lsum[4] = {0.f, 0.f, 0.f, 0.f};   // per-lane partial; reduced at epilogue

    auto stage = [&](int kv0) {
        __syncthreads();
        #pragma unroll
        for (int i = 0; i < 2; ++i) {
            int cbase = i * 256 + wave * 64;
            int slot = cbase + lane;
            int row = slot >> 3, c = (slot & 7) ^ (row & 7);
            glds16(Kb + (size_t)(kv0 + row) * DMODEL + c * 8, (char*)k_sh + (size_t)cbase * 16);
        }
        #pragma unroll
        for (int s = 0; s < 2; ++s) {
            int slot = tid + s * 256;
            int row = slot >> 3, grp = slot & 7;
            bf16x8_t vv8 = *(const bf16x8_t*)(Vb + (size_t)(kv0 + row) * DMODEL + grp * 8);
            int sh = (row + grp * 8) & 63;
            #pragma unroll
            for (int j = 0; j < 8; ++j)
                v_sh[(grp * 8 + j) * 64 + sh] = vv8[j];
        }
        __syncthreads();
    };

    auto body = [&](auto needmask_c, int kv0) {
        constexpr bool NEEDMASK = decltype(needmask_c)::value;
        // ---- S = Q K^T ----
        f32x4_t sf[4] = {};
        #pragma unroll
        for (int ks = 0; ks < 2; ++ks)
            #pragma unroll
            for (int n = 0; n < 4; ++n) {
                int row = n * 16 + l15;
                bf16x8_t kf = *(const bf16x8_t*)(k_sh + row * 64 + (((ks * 4 + lhi) ^ (row & 7)) * 8));
                sf[n] = MFMA16(qf[ks], kf, sf[n]);
            }

        // ---- scale (exp2 domain) + mask (diag only) + row max ----
        const int qrow_base = qbase + lhi * 4;
        float pmax[4];
        #pragma unroll
        for (int r = 0; r < 4; ++r) {
            float mx = -3.0e38f;
            #pragma unroll
            for (int n = 0; n < 4; ++n) {
                float sv = sf[n][r] * SCL2;
                if constexpr (NEEDMASK)
                    if (kv0 + n * 16 + l15 > qrow_base + r) sv = -1.0e30f;
                sf[n][r] = sv;
                mx = fmaxf(mx, sv);
            }
            pmax[r] = mx;
        }
        #pragma unroll
        for (int r = 0; r < 4; ++r)
            #pragma unroll
            for (int off = 1; off < 16; off <<= 1)
                pmax[r] = fmaxf(pmax[r], __shfl_xor(pmax[r], off, 64));

        // ---- defer-rescale vote (T13, THR=0) ----
        bool grew = (pmax[0] > m2[0]) || (pmax[1] > m2[1]) ||
                    (pmax[2] > m2[2]) || (pmax[3] > m2[3]);
        if (__any((int)grew)) {
            #pragma unroll
            for (int r = 0; r < 4; ++r) {
                float mnew = fmaxf(m2[r], pmax[r]);
                float sfac = exp2_fast(m2[r] - mnew);
                m2[r] = mnew;
                lsum[r] *= sfac;
                #pragma unroll
                for (int n = 0; n < 4; ++n) acc[n][r] *= sfac;
            }
        }

        // ---- P = exp2(S - m), per-lane partial l ----
        #pragma unroll
        for (int r = 0; r < 4; ++r) {
            float rs = 0.f;
            #pragma unroll
            for (int n = 0; n < 4; ++n) {
                float pv = exp2_fast(sf[n][r] - m2[r]);
                sf[n][r] = pv;
                rs += pv;
            }
            lsum[r] += rs;
        }

        // ---- P -> per-wave rotated LDS (same-wave in-order, no barrier) ----
        #pragma unroll
        for (int r = 0; r < 4; ++r)
            #pragma unroll
            for (int n = 0; n < 4; ++n)
                p_sh[wave][(lhi * 4 + r) * LDP + ((n * 16 + l15 + ((lhi >> 1) << 3)) & 63)]
                    = (__bf16)sf[n][r];

        // ---- ctx += P V ----
        #pragma unroll
        for (int ks = 0; ks < 2; ++ks) {
            bf16x8_t pa = *(const bf16x8_t*)(
                &p_sh[wave][l15 * LDP + ((ks * 32 + lhi * 8 + ((l15 >> 3) << 3)) & 63)]);
            #pragma unroll
            for (int n = 0; n < 4; ++n) {
                int d = n * 16 + l15;
                int sh = (ks * 32 + lhi * 8 + ((d >> 3) << 3)) & 63;
                bf16x8_t vf = *(const bf16x8_t*)(v_sh + d * 64 + sh);
                acc[n] = MFMA16(pa, vf, acc[n]);
            }
        }
    };

    for (int t = 0; t < p; ++t) {
        stage(t * 64);
        body(std::integral_constant<bool, false>{}, t * 64);
    }
    stage(p * 64);
    body(std::integral_constant<bool, true>{}, p * 64);

    // ---- epilogue: reduce per-lane l across the 16 lanes of each row, store ----
    #pragma unroll
    for (int r = 0; r < 4; ++r) {
        #pragma unroll
        for (int off = 1; off < 16; off <<= 1)
            lsum[r] += __shfl_xor(lsum[r], off, 64);
    }
    __bf16* Ob = Om + (size_t)b * SEQ * DMODEL + h * DK;
    #pragma unroll
    for (int n = 0; n < 4; ++n)
        #pragma unroll
        for (int r = 0; r < 4; ++r) {
            int row = qbase + lhi * 4 + r;
            Ob[(size_t)row * DMODEL + n * 16 + l15] = (__bf16)(acc[n][r] / lsum[r]);
        }
}

// ================= launch ============================================================
extern "C" void kernel_launch(void* const* d_in, const int* in_sizes, int n_in,
                              void* d_out, int out_size, void* d_ws, size_t ws_size,
                              hipStream_t stream)
{
    const float* q  = (const float*)d_in[0];
    const float* k  = (const float*)d_in[1];
    const float* v  = (const float*)d_in[2];
    const float* wq = (const float*)d_in[4];
    const float* wk = (const float*)d_in[5];
    const float* wv = (const float*)d_in[6];
    const float* wo = (const float*)d_in[7];
    float* out = (float*)d_out;

    const size_t mat = (size_t)MTOT * DMODEL;
    __bf16* Qw = (__bf16*)d_ws;
    __bf16* Kw = Qw + mat;
    __bf16* Vw = Kw + mat;
    __bf16* Cw = Vw + mat;
    __bf16* Wc = Cw + mat;   // 4 x 2MB bf16 weights

    dim3 blk(256);
    cvt_w_kernel<<<dim3(512, 4), blk, 0, stream>>>(wq, wk, wv, wo, Wc);
    proj_qkv_kernel<<<dim3(DMODEL / 128, MTOT / 128, 3), blk, 0, stream>>>(
        q, k, v, Wc, Qw, Kw, Vw);
    attn_kernel<<<dim3(32, 32), blk, 0, stream>>>(Qw, Kw, Vw, Cw);
    proj_out_kernel<<<dim3(DMODEL / 128, MTOT / 128), blk, 0, stream>>>(
        Cw, Wc + 3 * DMODEL * DMODEL, out);
}

// Round 7
// 136.688 us; speedup vs baseline: 1.9571x; 1.3129x over previous
//
#include <hip/hip_runtime.h>
#include <hip/hip_bf16.h>
#include <type_traits>

using bf16x8_t = __attribute__((ext_vector_type(8))) __bf16;
using f32x4_t  = __attribute__((ext_vector_type(4))) float;

#define MFMA16(a, b, c) __builtin_amdgcn_mfma_f32_16x16x32_bf16((a), (b), (c), 0, 0, 0)

constexpr int BATCH   = 2;
constexpr int SEQ     = 2048;
constexpr int DMODEL  = 1024;
constexpr int DK      = 64;
constexpr int MTOT    = BATCH * SEQ;
// softmax in exp2 domain: scores pre-multiplied by 1/sqrt(64) * log2(e)
constexpr float SCL2 = 0.125f * 1.44269504088896f;

// ---- async global->LDS, 16B/lane; dest = wave-uniform base + lane*16 (m104) ----
typedef const __attribute__((address_space(1))) unsigned int ga_u32;
typedef __attribute__((address_space(3))) unsigned int ls_u32;
__device__ __forceinline__ void glds16(const void* g, void* l) {
    __builtin_amdgcn_global_load_lds((ga_u32*)g, (ls_u32*)l, 16, 0, 0);
}

// v_exp_f32 IS exp2
__device__ __forceinline__ float exp2_fast(float x) {
    float r;
    asm volatile("v_exp_f32 %0, %1" : "=v"(r) : "v"(x));
    return r;
}

__device__ __forceinline__ bf16x8_t cvt8(const float* __restrict__ p) {
    f32x4_t a = *(const f32x4_t*)p;
    f32x4_t b = *(const f32x4_t*)(p + 4);
    bf16x8_t r;
    r[0] = (__bf16)a[0]; r[1] = (__bf16)a[1]; r[2] = (__bf16)a[2]; r[3] = (__bf16)a[3];
    r[4] = (__bf16)b[0]; r[5] = (__bf16)b[1]; r[6] = (__bf16)b[2]; r[7] = (__bf16)b[3];
    return r;
}

// pack 8 fp32 (two xor-swizzled 16B chunks of a 128B LDS row) -> bf16x8 fragment
__device__ __forceinline__ bf16x8_t pack_row_frag(const float* row_base, int row, int lhi) {
    f32x4_t v0 = *(const f32x4_t*)(row_base + ((lhi * 2 + 0) ^ (row & 7)) * 4);
    f32x4_t v1 = *(const f32x4_t*)(row_base + ((lhi * 2 + 1) ^ (row & 7)) * 4);
    bf16x8_t r;
    r[0] = (__bf16)v0[0]; r[1] = (__bf16)v0[1]; r[2] = (__bf16)v0[2]; r[3] = (__bf16)v0[3];
    r[4] = (__bf16)v1[0]; r[5] = (__bf16)v1[1]; r[6] = (__bf16)v1[2]; r[7] = (__bf16)v1[3];
    return r;
}

// ---- weight fp32 -> bf16 convert: grid (512, 4), 256 thr, 8 elems/thread ----
__global__ __launch_bounds__(256) void cvt_w_kernel(
    const float* __restrict__ w0, const float* __restrict__ w1,
    const float* __restrict__ w2, const float* __restrict__ w3, __bf16* __restrict__ dst)
{
    const float* srcs[4] = {w0, w1, w2, w3};
    const float* s = srcs[blockIdx.y];
    __bf16* d = dst + (size_t)blockIdx.y * (DMODEL * DMODEL);
    size_t i = ((size_t)blockIdx.x * 256 + threadIdx.x) * 8;
    *(bf16x8_t*)(d + i) = cvt8(s + i);
}

// ================= GEMM: C[M,N] = A[M,K] * Bt[N,K]^T ================================
// 128x128 tile, BK=32, 4 waves (2x2). 2-phase pipeline: double-buffered LDS, all
// staging via global_load_lds, prefetch(next) issued BEFORE the MFMA body, ONE
// barrier per K-step (compiler adds vmcnt(0) drain there).
template<bool A_BF16, bool C_F32>
__device__ __forceinline__ void gemm_body(
    const void* __restrict__ Ap, const __bf16* __restrict__ Bt,
    void* __restrict__ Cp, int m0, int n0)
{
    constexpr int K = DMODEL, N = DMODEL;
    constexpr int A_LS_BYTES = A_BF16 ? 8192 : 16384;
    constexpr int BUF_BYTES  = A_LS_BYTES + 8192;
    __shared__ __align__(16) char smem[2][BUF_BYTES];

    const int tid  = threadIdx.x;
    const int wave = tid >> 6, lane = tid & 63;
    const int wm = wave >> 1, wn = wave & 1;
    const int l15 = lane & 15, lhi = lane >> 4;

    auto stage = [&](int k0, int buf) {
        char* a_ls = smem[buf];
        char* b_ls = smem[buf] + A_LS_BYTES;
        if constexpr (A_BF16) {
            const __bf16* Ab = (const __bf16*)Ap;
            #pragma unroll
            for (int i = 0; i < 2; ++i) {
                int cbase = i * 256 + wave * 64;
                int slot = cbase + lane;
                int row = slot >> 2, c = slot & 3;
                int cs = (c + 4 - ((row >> 1) & 3)) & 3;
                glds16(Ab + (size_t)(m0 + row) * K + k0 + cs * 8, a_ls + (size_t)cbase * 16);
            }
        } else {
            const float* Af = (const float*)Ap;
            #pragma unroll
            for (int i = 0; i < 4; ++i) {
                int cbase = i * 256 + wave * 64;
                int slot = cbase + lane;
                int row = slot >> 3, c = (slot & 7) ^ (row & 7);
                glds16(Af + (size_t)(m0 + row) * K + k0 + c * 4, a_ls + (size_t)cbase * 16);
            }
        }
        #pragma unroll
        for (int i = 0; i < 2; ++i) {
            int cbase = i * 256 + wave * 64;
            int slot = cbase + lane;
            int row = slot >> 2, c = slot & 3;
            int cs = (c + 4 - ((row >> 1) & 3)) & 3;
            glds16(Bt + (size_t)(n0 + row) * K + k0 + cs * 8, b_ls + (size_t)cbase * 16);
        }
    };

    f32x4_t acc[4][4] = {};
    stage(0, 0);
    __syncthreads();

    for (int st = 0; st < K / 32; ++st) {
        if (st < K / 32 - 1) stage((st + 1) * 32, (st + 1) & 1);   // prefetch first

        const char*   a_ls = smem[st & 1];
        const __bf16* b_ls = (const __bf16*)(smem[st & 1] + A_LS_BYTES);

        bf16x8_t af[4], bfr[4];
        #pragma unroll
        for (int i = 0; i < 4; ++i) {
            int row = wm * 64 + i * 16 + l15;
            if constexpr (A_BF16) {
                int lc = (lhi + (row >> 1)) & 3;
                af[i] = *(const bf16x8_t*)((const __bf16*)a_ls + row * 32 + lc * 8);
            } else {
                af[i] = pack_row_frag((const float*)a_ls + row * 32, row, lhi);
            }
        }
        #pragma unroll
        for (int j = 0; j < 4; ++j) {
            int row = wn * 64 + j * 16 + l15;
            int lc = (lhi + (row >> 1)) & 3;
            bfr[j] = *(const bf16x8_t*)(b_ls + row * 32 + lc * 8);
        }
        #pragma unroll
        for (int i = 0; i < 4; ++i)
            #pragma unroll
            for (int j = 0; j < 4; ++j)
                acc[i][j] = MFMA16(af[i], bfr[j], acc[i][j]);

        __syncthreads();   // drains prefetch vmcnt; protects buf swap
    }

    // C/D layout (m89): col = lane&15, row = (lane>>4)*4 + reg
    #pragma unroll
    for (int i = 0; i < 4; ++i)
        #pragma unroll
        for (int j = 0; j < 4; ++j)
            #pragma unroll
            for (int r = 0; r < 4; ++r) {
                int row = m0 + wm * 64 + i * 16 + lhi * 4 + r;
                int col = n0 + wn * 64 + j * 16 + l15;
                if constexpr (C_F32)
                    ((float*)Cp)[(size_t)row * N + col] = acc[i][j][r];
                else
                    ((__bf16*)Cp)[(size_t)row * N + col] = (__bf16)acc[i][j][r];
            }
}

// QKV projection: grid 768 blocks flat; XCD-swizzled (each XCD: 12 A-panels + 1 weight)
__global__ __launch_bounds__(256) void proj_qkv_kernel(
    const float* __restrict__ xq, const float* __restrict__ xk, const float* __restrict__ xv,
    const __bf16* __restrict__ wc,
    __bf16* __restrict__ oq, __bf16* __restrict__ ok, __bf16* __restrict__ ov)
{
    int lid = blockIdx.x + 8 * blockIdx.y + 256 * blockIdx.z;
    int nid = (lid & 7) * 96 + (lid >> 3);          // bijective: 768 = 8*96
    int z = nid >> 8, rem = nid & 255;
    int m0 = (rem >> 3) * 128, n0 = (rem & 7) * 128;

    const float* A; const __bf16* Bt; __bf16* C;
    if (z == 0)      { A = xq; Bt = wc;                       C = oq; }
    else if (z == 1) { A = xk; Bt = wc + DMODEL * DMODEL;     C = ok; }
    else             { A = xv; Bt = wc + 2 * DMODEL * DMODEL; C = ov; }
    gemm_body<false, false>(A, Bt, C, m0, n0);
}

__global__ __launch_bounds__(256) void proj_out_kernel(
    const __bf16* __restrict__ ctx, const __bf16* __restrict__ woc, float* __restrict__ out)
{
    int lid = blockIdx.x + 8 * blockIdx.y;
    int nid = (lid & 7) * 32 + (lid >> 3);          // bijective: 256 = 8*32
    gemm_body<true, true>(ctx, woc, out, (nid >> 3) * 128, (nid & 7) * 128);
}

// ================= Flash attention (causal, pipelined) ===============================
// 1024 blocks, 256 thr = 4 waves, one 64-row q-tile each. XCD swizzle groups 4 heads
// per XCD (KV 2MB -> L2); depth p = (y&1) ? 31-x : x keeps co-resident blocks at
// complementary depths. 2-phase pipeline: K double-buffered via glds16 (XOR chunk
// swizzle); V single-buffered [d][72] with 16B rotation, staged global->reg at top
// of body t, reg->LDS after the main barrier (T14 issue-early/write-late).
__global__ __launch_bounds__(256, 4) void attn_kernel(
    const __bf16* __restrict__ Qm, const __bf16* __restrict__ Km,
    const __bf16* __restrict__ Vm, __bf16* __restrict__ Om)
{
    constexpr int LDV = 72, LDP = 72;
    __shared__ __bf16 k_sh[2][64 * 64];   // dbuf; glds16, chunk xor (c^(row&7))
    __shared__ __bf16 v_sh[64 * LDV];     // (d,kv) at d*72 + ((kv+8*(d>>3))&63)
    __shared__ __bf16 p_sh[4][16 * LDP];  // per-wave, rotated on q>>3

    const int tid  = threadIdx.x;
    const int wave = tid >> 6, lane = tid & 63;
    const int l15 = lane & 15, lhi = lane >> 4;

    int old = blockIdx.x + 32 * blockIdx.y;
    int nid = (old & 7) * 128 + (old >> 3);          // bijective: 1024 = 8*128
    const int x = nid & 31, y = nid >> 5;
    const int p = (y & 1) ? 31 - x : x;              // q-tile depth, CU-balanced
    const int q0 = p * 64;
    const int b = y >> 4, h = y & 15;

    const __bf16* Qb = Qm + (size_t)b * SEQ * DMODEL + h * DK;
    const __bf16* Kb = Km + (size_t)b * SEQ * DMODEL + h * DK;
    const __bf16* Vb = Vm + (size_t)b * SEQ * DMODEL + h * DK;

    const int qbase = q0 + wave * 16;

    // Q fragments (A layout: row = lane&15, k = (lane>>4)*8 + j)
    bf16x8_t qf[2];
    {
        const __bf16* qp = Qb + (size_t)(qbase + l15) * DMODEL + lhi * 8;
        qf[0] = *(const bf16x8_t*)qp;
        qf[1] = *(const bf16x8_t*)(qp + 32);
    }

    f32x4_t acc[4] = {};
    float m2[4] = {-INFINITY, -INFINITY, -INFINITY, -INFINITY};
    float lsum[4] = {0.f, 0.f, 0.f, 0.f};

    // ---- staging helpers ----
    const int vrow = tid >> 3, vgrp = tid & 7;       // V: thread owns rows vrow, vrow+32
    bf16x8_t vreg0, vreg1;

    auto stageK = [&](int kv0, int buf) {
        #pragma unroll
        for (int i = 0; i < 2; ++i) {
            int cbase = i * 256 + wave * 64;
            int slot = cbase + lane;
            int row = slot >> 3, c = (slot & 7) ^ (row & 7);
            glds16(Kb + (size_t)(kv0 + row) * DMODEL + c * 8,
                   (char*)k_sh[buf] + (size_t)cbase * 16);
        }
    };
    auto loadV = [&](int kv0) {
        vreg0 = *(const bf16x8_t*)(Vb + (size_t)(kv0 + vrow) * DMODEL + vgrp * 8);
        vreg1 = *(const bf16x8_t*)(Vb + (size_t)(kv0 + 32 + vrow) * DMODEL + vgrp * 8);
    };
    auto writeV = [&]() {
        int sh0 = (vrow + vgrp * 8) & 63;
        #pragma unroll
        for (int j = 0; j < 8; ++j) v_sh[(vgrp * 8 + j) * LDV + sh0] = vreg0[j];
        int sh1 = (vrow + 32 + vgrp * 8) & 63;
        #pragma unroll
        for (int j = 0; j < 8; ++j) v_sh[(vgrp * 8 + j) * LDV + sh1] = vreg1[j];
    };

    auto body = [&](auto needmask_c, int kv0, int cur) {
        constexpr bool NEEDMASK = decltype(needmask_c)::value;
        const __bf16* ks_buf = k_sh[cur];

        // ---- S = Q K^T ----
        f32x4_t sf[4] = {};
        #pragma unroll
        for (int ks = 0; ks < 2; ++ks)
            #pragma unroll
            for (int n = 0; n < 4; ++n) {
                int row = n * 16 + l15;
                bf16x8_t kf = *(const bf16x8_t*)(ks_buf + row * 64 + (((ks * 4 + lhi) ^ (row & 7)) * 8));
                sf[n] = MFMA16(qf[ks], kf, sf[n]);
            }

        // ---- scale (exp2 domain) + mask (diag only) + row max ----
        const int qrow_base = qbase + lhi * 4;
        float pmax[4];
        #pragma unroll
        for (int r = 0; r < 4; ++r) {
            float mx = -3.0e38f;
            #pragma unroll
            for (int n = 0; n < 4; ++n) {
                float sv = sf[n][r] * SCL2;
                if constexpr (NEEDMASK)
                    if (kv0 + n * 16 + l15 > qrow_base + r) sv = -1.0e30f;
                sf[n][r] = sv;
                mx = fmaxf(mx, sv);
            }
            pmax[r] = mx;
        }
        #pragma unroll
        for (int r = 0; r < 4; ++r)
            #pragma unroll
            for (int off = 1; off < 16; off <<= 1)
                pmax[r] = fmaxf(pmax[r], __shfl_xor(pmax[r], off, 64));

        // ---- defer-rescale vote (T13) ----
        bool grew = (pmax[0] > m2[0]) || (pmax[1] > m2[1]) ||
                    (pmax[2] > m2[2]) || (pmax[3] > m2[3]);
        if (__any((int)grew)) {
            #pragma unroll
            for (int r = 0; r < 4; ++r) {
                float mnew = fmaxf(m2[r], pmax[r]);
                float sfac = exp2_fast(m2[r] - mnew);
                m2[r] = mnew;
                lsum[r] *= sfac;
                #pragma unroll
                for (int n = 0; n < 4; ++n) acc[n][r] *= sfac;
            }
        }

        // ---- P = exp2(S - m), per-lane partial l ----
        #pragma unroll
        for (int r = 0; r < 4; ++r) {
            float rs = 0.f;
            #pragma unroll
            for (int n = 0; n < 4; ++n) {
                float pv = exp2_fast(sf[n][r] - m2[r]);
                sf[n][r] = pv;
                rs += pv;
            }
            lsum[r] += rs;
        }

        // ---- P -> per-wave rotated LDS (same-wave in-order, no barrier) ----
        #pragma unroll
        for (int r = 0; r < 4; ++r)
            #pragma unroll
            for (int n = 0; n < 4; ++n)
                p_sh[wave][(lhi * 4 + r) * LDP + ((n * 16 + l15 + ((lhi >> 1) << 3)) & 63)]
                    = (__bf16)sf[n][r];

        // ---- ctx += P V ----
        #pragma unroll
        for (int ks = 0; ks < 2; ++ks) {
            bf16x8_t pa = *(const bf16x8_t*)(
                &p_sh[wave][l15 * LDP + ((ks * 32 + lhi * 8 + ((l15 >> 3) << 3)) & 63)]);
            #pragma unroll
            for (int n = 0; n < 4; ++n) {
                int d = n * 16 + l15;
                int rot = (ks * 32 + lhi * 8 + ((d >> 3) << 3)) & 63;
                bf16x8_t vf = *(const bf16x8_t*)(v_sh + d * LDV + rot);
                acc[n] = MFMA16(pa, vf, acc[n]);
            }
        }
    };

    // ---- prologue: stage tile 0 ----
    stageK(0, 0);
    loadV(0);
    __syncthreads();     // K glds drained (compiler vmcnt(0))
    writeV();            // compiler waits vmcnt for vregs
    __syncthreads();     // V visible

    // ---- pipelined main loop ----
    for (int t = 0; t < p; ++t) {
        int cur = t & 1;
        stageK((t + 1) * 64, cur ^ 1);   // prefetch issue first  (FIX: was t+1)
        loadV((t + 1) * 64);             //                      (FIX: was t+1)
        body(std::integral_constant<bool, false>{}, t * 64, cur);
        __syncthreads();          // PV reads done; next-K drained
        writeV();
        __syncthreads();          // next-V visible
    }
    body(std::integral_constant<bool, true>{}, p * 64, p & 1);

    // ---- epilogue ----
    #pragma unroll
    for (int r = 0; r < 4; ++r) {
        #pragma unroll
        for (int off = 1; off < 16; off <<= 1)
            lsum[r] += __shfl_xor(lsum[r], off, 64);
    }
    __bf16* Ob = Om + (size_t)b * SEQ * DMODEL + h * DK;
    #pragma unroll
    for (int n = 0; n < 4; ++n)
        #pragma unroll
        for (int r = 0; r < 4; ++r) {
            int row = qbase + lhi * 4 + r;
            Ob[(size_t)row * DMODEL + n * 16 + l15] = (__bf16)(acc[n][r] / lsum[r]);
        }
}

// ================= launch ============================================================
extern "C" void kernel_launch(void* const* d_in, const int* in_sizes, int n_in,
                              void* d_out, int out_size, void* d_ws, size_t ws_size,
                              hipStream_t stream)
{
    const float* q  = (const float*)d_in[0];
    const float* k  = (const float*)d_in[1];
    const float* v  = (const float*)d_in[2];
    const float* wq = (const float*)d_in[4];
    const float* wk = (const float*)d_in[5];
    const float* wv = (const float*)d_in[6];
    const float* wo = (const float*)d_in[7];
    float* out = (float*)d_out;

    const size_t mat = (size_t)MTOT * DMODEL;
    __bf16* Qw = (__bf16*)d_ws;
    __bf16* Kw = Qw + mat;
    __bf16* Vw = Kw + mat;
    __bf16* Cw = Vw + mat;
    __bf16* Wc = Cw + mat;   // 4 x 2MB bf16 weights

    dim3 blk(256);
    cvt_w_kernel<<<dim3(512, 4), blk, 0, stream>>>(wq, wk, wv, wo, Wc);
    proj_qkv_kernel<<<dim3(8, 32, 3), blk, 0, stream>>>(q, k, v, Wc, Qw, Kw, Vw);
    attn_kernel<<<dim3(32, 32), blk, 0, stream>>>(Qw, Kw, Vw, Cw);
    proj_out_kernel<<<dim3(8, 32), blk, 0, stream>>>(Cw, Wc + 3 * DMODEL * DMODEL, out);
}

// Round 8
// 129.716 us; speedup vs baseline: 2.0623x; 1.0537x over previous
//
#include <hip/hip_runtime.h>
#include <hip/hip_bf16.h>
#include <type_traits>

using bf16x8_t = __attribute__((ext_vector_type(8))) __bf16;
using bf16x4_t = __attribute__((ext_vector_type(4))) __bf16;
using f32x4_t  = __attribute__((ext_vector_type(4))) float;

#define MFMA16(a, b, c) __builtin_amdgcn_mfma_f32_16x16x32_bf16((a), (b), (c), 0, 0, 0)

constexpr int BATCH   = 2;
constexpr int SEQ     = 2048;
constexpr int DMODEL  = 1024;
constexpr int DK      = 64;
constexpr int MTOT    = BATCH * SEQ;
// softmax in exp2 domain: Q pre-scaled at projection by 1/sqrt(64) * log2(e)
constexpr float SCL2 = 0.125f * 1.44269504088896f;

// ---- async global->LDS, 16B/lane; dest = wave-uniform base + lane*16 (m104) ----
typedef const __attribute__((address_space(1))) unsigned int ga_u32;
typedef __attribute__((address_space(3))) unsigned int ls_u32;
__device__ __forceinline__ void glds16(const void* g, void* l) {
    __builtin_amdgcn_global_load_lds((ga_u32*)g, (ls_u32*)l, 16, 0, 0);
}

// v_exp_f32 IS exp2
__device__ __forceinline__ float exp2_fast(float x) {
    float r;
    asm volatile("v_exp_f32 %0, %1" : "=v"(r) : "v"(x));
    return r;
}

__device__ __forceinline__ bf16x8_t cvt8(const float* __restrict__ p) {
    f32x4_t a = *(const f32x4_t*)p;
    f32x4_t b = *(const f32x4_t*)(p + 4);
    bf16x8_t r;
    r[0] = (__bf16)a[0]; r[1] = (__bf16)a[1]; r[2] = (__bf16)a[2]; r[3] = (__bf16)a[3];
    r[4] = (__bf16)b[0]; r[5] = (__bf16)b[1]; r[6] = (__bf16)b[2]; r[7] = (__bf16)b[3];
    return r;
}

// ---- weight fp32 -> bf16 convert: grid (512, 4), 256 thr, 8 elems/thread ----
__global__ __launch_bounds__(256) void cvt_w_kernel(
    const float* __restrict__ w0, const float* __restrict__ w1,
    const float* __restrict__ w2, const float* __restrict__ w3, __bf16* __restrict__ dst)
{
    const float* srcs[4] = {w0, w1, w2, w3};
    const float* s = srcs[blockIdx.y];
    __bf16* d = dst + (size_t)blockIdx.y * (DMODEL * DMODEL);
    size_t i = ((size_t)blockIdx.x * 256 + threadIdx.x) * 8;
    *(bf16x8_t*)(d + i) = cvt8(s + i);
}

// ================= GEMM: C[M,N] = A[M,K] * Bt[N,K]^T ================================
// 128x128 tile, BK=32, 4 waves (2x2). 2-phase pipeline, LDS 2 x 16 KB (bf16 A+B) ->
// 5 blocks/CU. A fp32: reg-staged (global->reg at top of step, cvt->bf16, ds_write
// after MFMA body = T14 issue-early/write-late). A bf16 and B: glds16. Add-rotate
// chunk swizzle (physical = (logical + (row>>1)) & 3) on both store and read.
template<bool A_BF16, bool C_F32>
__device__ __forceinline__ void gemm_body(
    const void* __restrict__ Ap, const __bf16* __restrict__ Bt,
    void* __restrict__ Cp, int m0, int n0, float cscale)
{
    constexpr int K = DMODEL, N = DMODEL;
    constexpr int NSTEPS = K / 32;
    __shared__ __align__(16) char smem[2][16384];   // per buf: A 8 KB + B 8 KB

    const int tid  = threadIdx.x;
    const int wave = tid >> 6, lane = tid & 63;
    const int wm = wave >> 1, wn = wave & 1;
    const int l15 = lane & 15, lhi = lane >> 4;

    auto glds_A_bf16 = [&](int k0, int buf) {
        const __bf16* Ab = (const __bf16*)Ap;
        #pragma unroll
        for (int i = 0; i < 2; ++i) {
            int cbase = i * 256 + wave * 64;
            int slot = cbase + lane;
            int row = slot >> 2, c = slot & 3;
            int cs = (c + 4 - ((row >> 1) & 3)) & 3;
            glds16(Ab + (size_t)(m0 + row) * K + k0 + cs * 8, smem[buf] + (size_t)cbase * 16);
        }
    };
    auto glds_B = [&](int k0, int buf) {
        #pragma unroll
        for (int i = 0; i < 2; ++i) {
            int cbase = i * 256 + wave * 64;
            int slot = cbase + lane;
            int row = slot >> 2, c = slot & 3;
            int cs = (c + 4 - ((row >> 1) & 3)) & 3;
            glds16(Bt + (size_t)(n0 + row) * K + k0 + cs * 8,
                   smem[buf] + 8192 + (size_t)cbase * 16);
        }
    };
    auto load_A_f32 = [&](int k0, f32x4_t (&ar)[4]) {
        const float* Af = (const float*)Ap;
        #pragma unroll
        for (int i = 0; i < 4; ++i) {
            int g = i * 256 + tid;              // linear 16B chunk: [128 rows][8 chunks]
            int row = g >> 3, c = g & 7;
            ar[i] = *(const f32x4_t*)(Af + (size_t)(m0 + row) * K + k0 + c * 4);
        }
    };
    auto write_A_f32 = [&](const f32x4_t (&ar)[4], int buf) {
        __bf16* a_ls = (__bf16*)smem[buf];
        #pragma unroll
        for (int i = 0; i < 4; ++i) {
            int g = i * 256 + tid;
            int row = g >> 3, c = g & 7;
            int pc = ((c >> 1) + ((row >> 1) & 3)) & 3;   // 8-elem chunk add-rotate
            bf16x4_t w;
            w[0] = (__bf16)ar[i][0]; w[1] = (__bf16)ar[i][1];
            w[2] = (__bf16)ar[i][2]; w[3] = (__bf16)ar[i][3];
            *(bf16x4_t*)(a_ls + row * 32 + pc * 8 + (c & 1) * 4) = w;
        }
    };

    f32x4_t acc[4][4] = {};

    // ---- prologue: stage tile 0 ----
    {
        f32x4_t ar0[4];
        if constexpr (A_BF16) glds_A_bf16(0, 0);
        else                  load_A_f32(0, ar0);
        glds_B(0, 0);
        if constexpr (!A_BF16) write_A_f32(ar0, 0);
    }
    __syncthreads();

    for (int st = 0; st < NSTEPS; ++st) {
        const int cur = st & 1;
        const bool have_next = (st + 1 < NSTEPS);
        f32x4_t areg[4];
        if (have_next) {
            const int k1 = (st + 1) * 32;
            if constexpr (A_BF16) glds_A_bf16(k1, cur ^ 1);
            else                  load_A_f32(k1, areg);
            glds_B(k1, cur ^ 1);
        }

        const __bf16* a_ls = (const __bf16*)smem[cur];
        const __bf16* b_ls = (const __bf16*)(smem[cur] + 8192);
        bf16x8_t af[4], bfr[4];
        #pragma unroll
        for (int i = 0; i < 4; ++i) {
            int row = wm * 64 + i * 16 + l15;
            int lc = (lhi + (row >> 1)) & 3;
            af[i] = *(const bf16x8_t*)(a_ls + row * 32 + lc * 8);
        }
        #pragma unroll
        for (int j = 0; j < 4; ++j) {
            int row = wn * 64 + j * 16 + l15;
            int lc = (lhi + (row >> 1)) & 3;
            bfr[j] = *(const bf16x8_t*)(b_ls + row * 32 + lc * 8);
        }
        #pragma unroll
        for (int i = 0; i < 4; ++i)
            #pragma unroll
            for (int j = 0; j < 4; ++j)
                acc[i][j] = MFMA16(af[i], bfr[j], acc[i][j]);

        if (have_next) {
            if constexpr (!A_BF16) write_A_f32(areg, cur ^ 1);
            __syncthreads();   // drains glds vmcnt + ds_writes; protects buf swap
        }
    }

    // C/D layout (m89): col = lane&15, row = (lane>>4)*4 + reg
    #pragma unroll
    for (int i = 0; i < 4; ++i)
        #pragma unroll
        for (int j = 0; j < 4; ++j)
            #pragma unroll
            for (int r = 0; r < 4; ++r) {
                int row = m0 + wm * 64 + i * 16 + lhi * 4 + r;
                int col = n0 + wn * 64 + j * 16 + l15;
                float v = acc[i][j][r] * cscale;
                if constexpr (C_F32)
                    ((float*)Cp)[(size_t)row * N + col] = v;
                else
                    ((__bf16*)Cp)[(size_t)row * N + col] = (__bf16)v;
            }
}

// QKV projection: grid 768 blocks flat; XCD-swizzled (each XCD: 12 A-panels + 1 weight)
__global__ __launch_bounds__(256) void proj_qkv_kernel(
    const float* __restrict__ xq, const float* __restrict__ xk, const float* __restrict__ xv,
    const __bf16* __restrict__ wc,
    __bf16* __restrict__ oq, __bf16* __restrict__ ok, __bf16* __restrict__ ov)
{
    int lid = blockIdx.x + 8 * blockIdx.y + 256 * blockIdx.z;
    int nid = (lid & 7) * 96 + (lid >> 3);          // bijective: 768 = 8*96
    int z = nid >> 8, rem = nid & 255;
    int m0 = (rem >> 3) * 128, n0 = (rem & 7) * 128;

    const float* A; const __bf16* Bt; __bf16* C; float cs;
    if (z == 0)      { A = xq; Bt = wc;                       C = oq; cs = SCL2; }
    else if (z == 1) { A = xk; Bt = wc + DMODEL * DMODEL;     C = ok; cs = 1.0f; }
    else             { A = xv; Bt = wc + 2 * DMODEL * DMODEL; C = ov; cs = 1.0f; }
    gemm_body<false, false>(A, Bt, C, m0, n0, cs);
}

__global__ __launch_bounds__(256) void proj_out_kernel(
    const __bf16* __restrict__ ctx, const __bf16* __restrict__ woc, float* __restrict__ out)
{
    int lid = blockIdx.x + 8 * blockIdx.y;
    int nid = (lid & 7) * 32 + (lid >> 3);          // bijective: 256 = 8*32
    gemm_body<true, true>(ctx, woc, out, (nid >> 3) * 128, (nid & 7) * 128, 1.0f);
}

// ================= Flash attention (causal, pipelined) ===============================
// 1024 blocks, 256 thr = 4 waves, one 64-row q-tile each. XCD swizzle groups 4 heads
// per XCD; depth p = (y&1) ? 31-x : x balances co-resident blocks. 2-phase pipeline:
// K double-buffered glds16 (XOR chunk swizzle); V reg-staged (T14). Q pre-scaled by
// SCL2 at projection; softmax in exp2 domain; l-sum accumulated via MFMA with an
// all-ones B fragment (exactly matches PV numerator quantization); defer-rescale
// vote with THR=8 (P bounded by 2^8, fp32 acc safe).
__global__ __launch_bounds__(256, 4) void attn_kernel(
    const __bf16* __restrict__ Qm, const __bf16* __restrict__ Km,
    const __bf16* __restrict__ Vm, __bf16* __restrict__ Om)
{
    constexpr int LDV = 72, LDP = 72;
    __shared__ __bf16 k_sh[2][64 * 64];   // dbuf; glds16, chunk xor (c^(row&7))
    __shared__ __bf16 v_sh[64 * LDV];     // (d,kv) at d*72 + ((kv+8*(d>>3))&63)
    __shared__ __bf16 p_sh[4][16 * LDP];  // per-wave, rotated on q>>3

    const int tid  = threadIdx.x;
    const int wave = tid >> 6, lane = tid & 63;
    const int l15 = lane & 15, lhi = lane >> 4;

    int old = blockIdx.x + 32 * blockIdx.y;
    int nid = (old & 7) * 128 + (old >> 3);          // bijective: 1024 = 8*128
    const int x = nid & 31, y = nid >> 5;
    const int p = (y & 1) ? 31 - x : x;              // q-tile depth, CU-balanced
    const int q0 = p * 64;
    const int b = y >> 4, h = y & 15;

    const __bf16* Qb = Qm + (size_t)b * SEQ * DMODEL + h * DK;
    const __bf16* Kb = Km + (size_t)b * SEQ * DMODEL + h * DK;
    const __bf16* Vb = Vm + (size_t)b * SEQ * DMODEL + h * DK;

    const int qbase = q0 + wave * 16;

    // Q fragments (A layout: row = lane&15, k = (lane>>4)*8 + j); pre-scaled by SCL2
    bf16x8_t qf[2];
    {
        const __bf16* qp = Qb + (size_t)(qbase + l15) * DMODEL + lhi * 8;
        qf[0] = *(const bf16x8_t*)qp;
        qf[1] = *(const bf16x8_t*)(qp + 32);
    }
    bf16x8_t onesf;
    #pragma unroll
    for (int j = 0; j < 8; ++j) onesf[j] = (__bf16)1.0f;

    f32x4_t acc[4] = {};
    f32x4_t acc_l = {};   // row-sum accumulator via ones-MFMA (replicated over l15)
    float m2[4] = {-INFINITY, -INFINITY, -INFINITY, -INFINITY};

    // ---- staging helpers ----
    const int vrow = tid >> 3, vgrp = tid & 7;       // V: thread owns rows vrow, vrow+32
    bf16x8_t vreg0, vreg1;

    auto stageK = [&](int kv0, int buf) {
        #pragma unroll
        for (int i = 0; i < 2; ++i) {
            int cbase = i * 256 + wave * 64;
            int slot = cbase + lane;
            int row = slot >> 3, c = (slot & 7) ^ (row & 7);
            glds16(Kb + (size_t)(kv0 + row) * DMODEL + c * 8,
                   (char*)k_sh[buf] + (size_t)cbase * 16);
        }
    };
    auto loadV = [&](int kv0) {
        vreg0 = *(const bf16x8_t*)(Vb + (size_t)(kv0 + vrow) * DMODEL + vgrp * 8);
        vreg1 = *(const bf16x8_t*)(Vb + (size_t)(kv0 + 32 + vrow) * DMODEL + vgrp * 8);
    };
    auto writeV = [&]() {
        int sh0 = (vrow + vgrp * 8) & 63;
        #pragma unroll
        for (int j = 0; j < 8; ++j) v_sh[(vgrp * 8 + j) * LDV + sh0] = vreg0[j];
        int sh1 = (vrow + 32 + vgrp * 8) & 63;
        #pragma unroll
        for (int j = 0; j < 8; ++j) v_sh[(vgrp * 8 + j) * LDV + sh1] = vreg1[j];
    };

    auto body = [&](auto needmask_c, int kv0, int cur) {
        constexpr bool NEEDMASK = decltype(needmask_c)::value;
        const __bf16* ks_buf = k_sh[cur];

        // ---- S = Q K^T (already in exp2 domain via pre-scaled Q) ----
        f32x4_t sf[4] = {};
        #pragma unroll
        for (int ks = 0; ks < 2; ++ks)
            #pragma unroll
            for (int n = 0; n < 4; ++n) {
                int row = n * 16 + l15;
                bf16x8_t kf = *(const bf16x8_t*)(ks_buf + row * 64 + (((ks * 4 + lhi) ^ (row & 7)) * 8));
                sf[n] = MFMA16(qf[ks], kf, sf[n]);
            }

        // ---- mask (diag only) + row max ----
        const int qrow_base = qbase + lhi * 4;
        float pmax[4];
        #pragma unroll
        for (int r = 0; r < 4; ++r) {
            float mx = -3.0e38f;
            #pragma unroll
            for (int n = 0; n < 4; ++n) {
                float sv = sf[n][r];
                if constexpr (NEEDMASK)
                    if (kv0 + n * 16 + l15 > qrow_base + r) sv = -1.0e30f;
                sf[n][r] = sv;
                mx = fmaxf(mx, sv);
            }
            pmax[r] = mx;
        }
        #pragma unroll
        for (int r = 0; r < 4; ++r)
            #pragma unroll
            for (int off = 1; off < 16; off <<= 1)
                pmax[r] = fmaxf(pmax[r], __shfl_xor(pmax[r], off, 64));

        // ---- defer-rescale vote (T13, THR=8 in exp2 domain) ----
        bool grew = (pmax[0] > m2[0] + 8.f) || (pmax[1] > m2[1] + 8.f) ||
                    (pmax[2] > m2[2] + 8.f) || (pmax[3] > m2[3] + 8.f);
        if (__any((int)grew)) {
            #pragma unroll
            for (int r = 0; r < 4; ++r) {
                float mnew = fmaxf(m2[r], pmax[r]);
                float sfac = exp2_fast(m2[r] - mnew);
                m2[r] = mnew;
                acc_l[r] *= sfac;
                #pragma unroll
                for (int n = 0; n < 4; ++n) acc[n][r] *= sfac;
            }
        }

        // ---- P = exp2(S - m) ----
        #pragma unroll
        for (int r = 0; r < 4; ++r)
            #pragma unroll
            for (int n = 0; n < 4; ++n)
                sf[n][r] = exp2_fast(sf[n][r] - m2[r]);

        // ---- P -> per-wave rotated LDS (same-wave in-order, no barrier) ----
        #pragma unroll
        for (int r = 0; r < 4; ++r)
            #pragma unroll
            for (int n = 0; n < 4; ++n)
                p_sh[wave][(lhi * 4 + r) * LDP + ((n * 16 + l15 + ((lhi >> 1) << 3)) & 63)]
                    = (__bf16)sf[n][r];

        // ---- ctx += P V ; l += P * ones (via MFMA) ----
        #pragma unroll
        for (int ks = 0; ks < 2; ++ks) {
            bf16x8_t pa = *(const bf16x8_t*)(
                &p_sh[wave][l15 * LDP + ((ks * 32 + lhi * 8 + ((l15 >> 3) << 3)) & 63)]);
            acc_l = MFMA16(pa, onesf, acc_l);
            #pragma unroll
            for (int n = 0; n < 4; ++n) {
                int d = n * 16 + l15;
                int rot = (ks * 32 + lhi * 8 + ((d >> 3) << 3)) & 63;
                bf16x8_t vf = *(const bf16x8_t*)(v_sh + d * LDV + rot);
                acc[n] = MFMA16(pa, vf, acc[n]);
            }
        }
    };

    // ---- prologue: stage tile 0 ----
    stageK(0, 0);
    loadV(0);
    __syncthreads();     // K glds drained (compiler vmcnt(0))
    writeV();            // compiler waits vmcnt for vregs
    __syncthreads();     // V visible

    // ---- pipelined main loop ----
    for (int t = 0; t < p; ++t) {
        int cur = t & 1;
        stageK((t + 1) * 64, cur ^ 1);   // prefetch issue first
        loadV((t + 1) * 64);
        body(std::integral_constant<bool, false>{}, t * 64, cur);
        __syncthreads();          // PV reads done; next-K drained
        writeV();
        __syncthreads();          // next-V visible
    }
    body(std::integral_constant<bool, true>{}, p * 64, p & 1);

    // ---- epilogue: acc_l already holds full row sums (replicated over l15) ----
    __bf16* Ob = Om + (size_t)b * SEQ * DMODEL + h * DK;
    #pragma unroll
    for (int n = 0; n < 4; ++n)
        #pragma unroll
        for (int r = 0; r < 4; ++r) {
            int row = qbase + lhi * 4 + r;
            Ob[(size_t)row * DMODEL + n * 16 + l15] = (__bf16)(acc[n][r] / acc_l[r]);
        }
}

// ================= launch ============================================================
extern "C" void kernel_launch(void* const* d_in, const int* in_sizes, int n_in,
                              void* d_out, int out_size, void* d_ws, size_t ws_size,
                              hipStream_t stream)
{
    const float* q  = (const float*)d_in[0];
    const float* k  = (const float*)d_in[1];
    const float* v  = (const float*)d_in[2];
    const float* wq = (const float*)d_in[4];
    const float* wk = (const float*)d_in[5];
    const float* wv = (const float*)d_in[6];
    const float* wo = (const float*)d_in[7];
    float* out = (float*)d_out;

    const size_t mat = (size_t)MTOT * DMODEL;
    __bf16* Qw = (__bf16*)d_ws;
    __bf16* Kw = Qw + mat;
    __bf16* Vw = Kw + mat;
    __bf16* Cw = Vw + mat;
    __bf16* Wc = Cw + mat;   // 4 x 2MB bf16 weights

    dim3 blk(256);
    cvt_w_kernel<<<dim3(512, 4), blk, 0, stream>>>(wq, wk, wv, wo, Wc);
    proj_qkv_kernel<<<dim3(8, 32, 3), blk, 0, stream>>>(q, k, v, Wc, Qw, Kw, Vw);
    attn_kernel<<<dim3(32, 32), blk, 0, stream>>>(Qw, Kw, Vw, Cw);
    proj_out_kernel<<<dim3(8, 32), blk, 0, stream>>>(Cw, Wc + 3 * DMODEL * DMODEL, out);
}